// Round 1
// baseline (612.820 us; speedup 1.0000x reference)
//
#include <hip/hip_runtime.h>
#include <stdint.h>
#include <math.h>

#define D 128
#define EDIM 5

// ======================= utility kernels =======================

__global__ void zero_int_kernel(int* __restrict__ p, int n) {
  int i = blockIdx.x * blockDim.x + threadIdx.x;
  if (i < n) p[i] = 0;
}

__global__ void hist_kernel(const int* __restrict__ ei, int* __restrict__ deg, int E) {
  int e = blockIdx.x * blockDim.x + threadIdx.x;
  if (e < E) atomicAdd(&deg[ei[(size_t)E + e]], 1);
}

__global__ __launch_bounds__(1024) void scan_kernel(const int* __restrict__ deg,
                                                    int* __restrict__ off, int n) {
  __shared__ int buf[1024];
  __shared__ int carry;
  const int t = threadIdx.x;
  if (t == 0) carry = 0;
  __syncthreads();
  for (int base = 0; base < n; base += 1024) {
    int i = base + t;
    int v = (i < n) ? deg[i] : 0;
    buf[t] = v;
    __syncthreads();
    for (int ofs = 1; ofs < 1024; ofs <<= 1) {
      int add = (t >= ofs) ? buf[t - ofs] : 0;
      __syncthreads();
      buf[t] += add;
      __syncthreads();
    }
    int my_carry = carry;
    if (i < n) off[i] = my_carry + buf[t] - v;   // exclusive
    int total = buf[1023];
    __syncthreads();
    if (t == 0) carry = my_carry + total;
    __syncthreads();
  }
  if (t == 0) off[n] = carry;
}

__global__ void scatter_kernel(const int* __restrict__ ei, const int* __restrict__ off,
                               int* __restrict__ cursor, int* __restrict__ ssrc,
                               int* __restrict__ seid, int E) {
  int e = blockIdx.x * blockDim.x + threadIdx.x;
  if (e >= E) return;
  int dst = ei[(size_t)E + e];
  int pos = off[dst] + atomicAdd(&cursor[dst], 1);
  ssrc[pos] = ei[e];
  seid[pos] = e;
}

// ======================= fused projections =======================
// q = (x@Wq^T + bq) * 0.125   -> q   [N][128] f32
// k =  x@Wk^T + bk            -> kv  [N][0:128] f32
// v =  x@Wv^T + bv            -> kv  [N][128:256] f32
// xr = x@Wskip^T + bskip      -> xr  [N][128] f32
__global__ __launch_bounds__(256) void proj_kernel(
    const float* __restrict__ x,
    const float* __restrict__ Wq, const float* __restrict__ bq,
    const float* __restrict__ Wk, const float* __restrict__ bk,
    const float* __restrict__ Wv, const float* __restrict__ bv,
    const float* __restrict__ Wr, const float* __restrict__ br,
    float* __restrict__ q, float* __restrict__ kv,
    float* __restrict__ xr, int N)
{
  __shared__ float xt[64][D];
  const int tid = threadIdx.x;
  const int rowBase = blockIdx.x * 64;

  for (int i = tid; i < 64 * (D / 4); i += 256) {
    int r = i >> 5;           // D/4 == 32
    int c4 = i & 31;
    int gr = rowBase + r;
    float4 v = make_float4(0.f, 0.f, 0.f, 0.f);
    if (gr < N) v = ((const float4*)(x + (size_t)gr * D))[c4];
    ((float4*)(xt[r]))[c4] = v;
  }
  __syncthreads();

  const int cg = tid & 31;    // cols 4cg .. 4cg+3
  const int rg = tid >> 5;    // rows 8rg .. 8rg+7
  const float* Ws[4] = {Wq, Wk, Wv, Wr};
  const float* bs[4] = {bq, bk, bv, br};

  for (int mtx = 0; mtx < 4; ++mtx) {
    const float* __restrict__ W = Ws[mtx];
    float acc[8][4];
#pragma unroll
    for (int r = 0; r < 8; ++r)
#pragma unroll
      for (int c = 0; c < 4; ++c) acc[r][c] = 0.f;

    for (int k = 0; k < D; k += 4) {
      float4 w0 = *(const float4*)(W + (size_t)(cg * 4 + 0) * D + k);
      float4 w1 = *(const float4*)(W + (size_t)(cg * 4 + 1) * D + k);
      float4 w2 = *(const float4*)(W + (size_t)(cg * 4 + 2) * D + k);
      float4 w3 = *(const float4*)(W + (size_t)(cg * 4 + 3) * D + k);
#pragma unroll
      for (int r = 0; r < 8; ++r) {
        float4 xv = *(const float4*)(&xt[rg * 8 + r][k]);
        acc[r][0] += xv.x * w0.x + xv.y * w0.y + xv.z * w0.z + xv.w * w0.w;
        acc[r][1] += xv.x * w1.x + xv.y * w1.y + xv.z * w1.z + xv.w * w1.w;
        acc[r][2] += xv.x * w2.x + xv.y * w2.y + xv.z * w2.z + xv.w * w2.w;
        acc[r][3] += xv.x * w3.x + xv.y * w3.y + xv.z * w3.z + xv.w * w3.w;
      }
    }

    float4 bias = *(const float4*)(bs[mtx] + cg * 4);
#pragma unroll
    for (int r = 0; r < 8; ++r) {
      int gr = rowBase + rg * 8 + r;
      if (gr >= N) continue;
      float o0 = acc[r][0] + bias.x;
      float o1 = acc[r][1] + bias.y;
      float o2 = acc[r][2] + bias.z;
      float o3 = acc[r][3] + bias.w;
      if (mtx == 0) {
        *(float4*)(q + (size_t)gr * D + cg * 4) =
            make_float4(o0 * 0.125f, o1 * 0.125f, o2 * 0.125f, o3 * 0.125f);
      } else if (mtx == 1) {
        *(float4*)(kv + (size_t)gr * 2 * D + cg * 4) = make_float4(o0, o1, o2, o3);
      } else if (mtx == 2) {
        *(float4*)(kv + (size_t)gr * 2 * D + D + cg * 4) = make_float4(o0, o1, o2, o3);
      } else {
        *(float4*)(xr + (size_t)gr * D + cg * 4) = make_float4(o0, o1, o2, o3);
      }
    }
  }
}

// ======================= per-node attention =======================
// One wave per node. Lane l owns dims {2l, 2l+1} (lanes 0-31: head 0, 32-63: head 1).
// Online softmax over the node's sorted incoming edges, fused beta gate.
// xr is read (x_r) and overwritten with the gated output.
__global__ __launch_bounds__(256) void node_attn_kernel(
    const float* __restrict__ q, const float* __restrict__ kv,
    float* __restrict__ xr,
    const float* __restrict__ edge_attr, const float* __restrict__ We,
    const float* __restrict__ Wb,
    const int* __restrict__ off, const int* __restrict__ ssrc,
    const int* __restrict__ seid, int N)
{
  __shared__ float weT[EDIM][D];
  for (int t = threadIdx.x; t < EDIM * D; t += blockDim.x) {
    int j = t / D, d = t % D;
    weT[j][d] = We[(size_t)d * EDIM + j];
  }
  __syncthreads();

  const int wave = threadIdx.x >> 6;
  const int lane = threadIdx.x & 63;
  const int node = blockIdx.x * 4 + wave;
  if (node >= N) return;

  const int d0 = lane * 2;
  const float2 ql = *(const float2*)(q + (size_t)node * D + d0);
  const int beg = off[node], end = off[node + 1];

  float m = -INFINITY, s = 0.f, ox = 0.f, oy = 0.f;

  for (int p = beg; p < end; ++p) {
    int src = ssrc[p];
    int eid = seid[p];
    const float* ea = edge_attr + (size_t)eid * EDIM;
    float e0 = 0.f, e1 = 0.f;
#pragma unroll
    for (int j = 0; j < EDIM; ++j) {
      float a = ea[j];
      e0 += a * weT[j][d0];
      e1 += a * weT[j][d0 + 1];
    }
    const float* kvp = kv + (size_t)src * 2 * D;
    float2 kk = *(const float2*)(kvp + d0);
    float2 vv = *(const float2*)(kvp + D + d0);
    float k0 = kk.x + e0, k1 = kk.y + e1;
    float v0 = vv.x + e0, v1 = vv.y + e1;

    float part = ql.x * k0 + ql.y * k1;
#pragma unroll
    for (int ofs = 1; ofs < 32; ofs <<= 1)
      part += __shfl_xor(part, ofs, 64);
    float alpha = part;                       // per half-wave (per head)

    float nm = fmaxf(m, alpha);
    float scale = __expf(m - nm);
    float pw = __expf(alpha - nm);
    s = s * scale + pw;
    ox = ox * scale + pw * v0;
    oy = oy * scale + pw * v1;
    m = nm;
  }

  float inv = (end > beg) ? (1.f / s) : 0.f;
  ox *= inv; oy *= inv;

  // beta gate: b = sum_d out[d]*(Wb[d]+Wb[256+d]) + xr[d]*(Wb[128+d]-Wb[256+d])
  float2 xrl = *(const float2*)(xr + (size_t)node * D + d0);
  float wb1a = Wb[d0] + Wb[256 + d0];
  float wb1b = Wb[d0 + 1] + Wb[256 + d0 + 1];
  float wb2a = Wb[128 + d0] - Wb[256 + d0];
  float wb2b = Wb[128 + d0 + 1] - Wb[256 + d0 + 1];
  float part = ox * wb1a + oy * wb1b + xrl.x * wb2a + xrl.y * wb2b;
#pragma unroll
  for (int ofs = 1; ofs < 64; ofs <<= 1)
    part += __shfl_xor(part, ofs, 64);
  float beta = 1.f / (1.f + __expf(-part));
  float g0 = beta * xrl.x + (1.f - beta) * ox;
  float g1 = beta * xrl.y + (1.f - beta) * oy;
  *(float2*)(xr + (size_t)node * D + d0) = make_float2(g0, g1);
}

// ======================= output projection =======================
__global__ __launch_bounds__(256) void outproj_kernel(
    const float* __restrict__ g, const float* __restrict__ W,
    const float* __restrict__ b, float* __restrict__ out, int N)
{
  __shared__ float xt[64][D];
  const int tid = threadIdx.x;
  const int rowBase = blockIdx.x * 64;

  for (int i = tid; i < 64 * (D / 4); i += 256) {
    int r = i >> 5;
    int c4 = i & 31;
    int gr = rowBase + r;
    float4 v = make_float4(0.f, 0.f, 0.f, 0.f);
    if (gr < N) v = ((const float4*)(g + (size_t)gr * D))[c4];
    ((float4*)(xt[r]))[c4] = v;
  }
  __syncthreads();

  const int cg = tid & 31;
  const int rg = tid >> 5;
  float acc[8][4];
#pragma unroll
  for (int r = 0; r < 8; ++r)
#pragma unroll
    for (int c = 0; c < 4; ++c) acc[r][c] = 0.f;

  for (int k = 0; k < D; k += 4) {
    float4 w0 = *(const float4*)(W + (size_t)(cg * 4 + 0) * D + k);
    float4 w1 = *(const float4*)(W + (size_t)(cg * 4 + 1) * D + k);
    float4 w2 = *(const float4*)(W + (size_t)(cg * 4 + 2) * D + k);
    float4 w3 = *(const float4*)(W + (size_t)(cg * 4 + 3) * D + k);
#pragma unroll
    for (int r = 0; r < 8; ++r) {
      float4 xv = *(const float4*)(&xt[rg * 8 + r][k]);
      acc[r][0] += xv.x * w0.x + xv.y * w0.y + xv.z * w0.z + xv.w * w0.w;
      acc[r][1] += xv.x * w1.x + xv.y * w1.y + xv.z * w1.z + xv.w * w1.w;
      acc[r][2] += xv.x * w2.x + xv.y * w2.y + xv.z * w2.z + xv.w * w2.w;
      acc[r][3] += xv.x * w3.x + xv.y * w3.y + xv.z * w3.z + xv.w * w3.w;
    }
  }

  float4 bias = *(const float4*)(b + cg * 4);
#pragma unroll
  for (int r = 0; r < 8; ++r) {
    int gr = rowBase + rg * 8 + r;
    if (gr >= N) continue;
    *(float4*)(out + (size_t)gr * D + cg * 4) =
        make_float4(acc[r][0] + bias.x, acc[r][1] + bias.y,
                    acc[r][2] + bias.z, acc[r][3] + bias.w);
  }
}

// ======================= launch =======================

extern "C" void kernel_launch(void* const* d_in, const int* in_sizes, int n_in,
                              void* d_out, int out_size, void* d_ws, size_t ws_size,
                              hipStream_t stream)
{
  const float* x  = (const float*)d_in[0];
  const int*   ei = (const int*)d_in[1];
  const float* ea = (const float*)d_in[2];
  const float* Wq = (const float*)d_in[3];
  const float* bq = (const float*)d_in[4];
  const float* Wk = (const float*)d_in[5];
  const float* bk = (const float*)d_in[6];
  const float* Wv = (const float*)d_in[7];
  const float* bv = (const float*)d_in[8];
  const float* We = (const float*)d_in[9];
  const float* Wr = (const float*)d_in[10];
  const float* br = (const float*)d_in[11];
  const float* Wb = (const float*)d_in[12];
  const float* Wp = (const float*)d_in[13];
  const float* bp = (const float*)d_in[14];

  const int N = in_sizes[0] / D;
  const int E = in_sizes[1] / 2;
  float* out = (float*)d_out;

  char* ws = (char*)d_ws;
  size_t o = 0;
  auto alloc = [&](size_t bytes) -> void* {
    void* p = ws + o;
    o = (o + bytes + 255) & ~(size_t)255;
    return p;
  };
  float* q      = (float*)alloc((size_t)N * D * sizeof(float));
  float* kv     = (float*)alloc((size_t)N * 2 * D * sizeof(float));
  float* xr     = (float*)alloc((size_t)N * D * sizeof(float));
  int*   deg    = (int*)alloc((size_t)N * sizeof(int));
  int*   cursor = (int*)alloc((size_t)N * sizeof(int));
  int*   offs   = (int*)alloc((size_t)(N + 1) * sizeof(int));
  int*   ssrc   = (int*)alloc((size_t)E * sizeof(int));
  int*   seid   = (int*)alloc((size_t)E * sizeof(int));

  // sort edges by dst: zero -> hist -> scan -> scatter
  zero_int_kernel<<<(2 * N + 255) / 256, 256, 0, stream>>>(deg, 2 * N); // deg+cursor contiguous? not guaranteed -> zero separately
  zero_int_kernel<<<(N + 255) / 256, 256, 0, stream>>>(cursor, N);
  hist_kernel<<<(E + 255) / 256, 256, 0, stream>>>(ei, deg, E);
  scan_kernel<<<1, 1024, 0, stream>>>(deg, offs, N);
  scatter_kernel<<<(E + 255) / 256, 256, 0, stream>>>(ei, offs, cursor, ssrc, seid, E);

  // projections (independent of the sort; ordered on the same stream anyway)
  proj_kernel<<<(N + 63) / 64, 256, 0, stream>>>(x, Wq, bq, Wk, bk, Wv, bv, Wr, br,
                                                 q, kv, xr, N);

  // per-node online-softmax attention + beta gate (gated result -> xr)
  node_attn_kernel<<<(N + 3) / 4, 256, 0, stream>>>(q, kv, xr, ea, We, Wb,
                                                    offs, ssrc, seid, N);

  // final projection
  outproj_kernel<<<(N + 63) / 64, 256, 0, stream>>>(xr, Wp, bp, out, N);
}

// Round 2
// 349.620 us; speedup vs baseline: 1.7528x; 1.7528x over previous
//
#include <hip/hip_runtime.h>
#include <stdint.h>
#include <math.h>

#define D 128
#define EDIM 5

typedef __attribute__((ext_vector_type(8))) short bf16x8;
typedef __attribute__((ext_vector_type(4))) float f32x4;

__device__ __forceinline__ ushort f2b(float f) {
  union { float f; uint u; } v; v.f = f;
  uint u = v.u;
  uint rounded = (u + 0x7fff + ((u >> 16) & 1)) >> 16;   // RNE
  // handle NaN conservatively (inputs are finite; keep cheap)
  return (ushort)rounded;
}
__device__ __forceinline__ float b2f(uint u) {
  union { uint u; float f; } v; v.u = u << 16; return v.f;
}

// ======================= utility kernels =======================

__global__ void zero_int_kernel(int* __restrict__ p, int n) {
  int i = blockIdx.x * blockDim.x + threadIdx.x;
  if (i < n) p[i] = 0;
}

__global__ void hist_kernel(const int* __restrict__ ei, int* __restrict__ deg, int E) {
  int e = blockIdx.x * blockDim.x + threadIdx.x;
  if (e < E) atomicAdd(&deg[ei[(size_t)E + e]], 1);
}

__global__ __launch_bounds__(1024) void scan_kernel(const int* __restrict__ deg,
                                                    int* __restrict__ off, int n) {
  __shared__ int buf[1024];
  __shared__ int carry;
  const int t = threadIdx.x;
  if (t == 0) carry = 0;
  __syncthreads();
  for (int base = 0; base < n; base += 1024) {
    int i = base + t;
    int v = (i < n) ? deg[i] : 0;
    buf[t] = v;
    __syncthreads();
    for (int ofs = 1; ofs < 1024; ofs <<= 1) {
      int add = (t >= ofs) ? buf[t - ofs] : 0;
      __syncthreads();
      buf[t] += add;
      __syncthreads();
    }
    int my_carry = carry;
    if (i < n) off[i] = my_carry + buf[t] - v;   // exclusive
    int total = buf[1023];
    __syncthreads();
    if (t == 0) carry = my_carry + total;
    __syncthreads();
  }
  if (t == 0) off[n] = carry;
}

__global__ void scatter_kernel(const int* __restrict__ ei, const int* __restrict__ off,
                               int* __restrict__ cursor, int* __restrict__ ssrc,
                               int* __restrict__ seid, int E) {
  int e = blockIdx.x * blockDim.x + threadIdx.x;
  if (e >= E) return;
  int dst = ei[(size_t)E + e];
  int pos = off[dst] + atomicAdd(&cursor[dst], 1);
  ssrc[pos] = ei[e];
  seid[pos] = e;
}

// ======================= conversions =======================

__global__ void cvt_x_kernel(const float* __restrict__ x, ushort* __restrict__ xb, int n4) {
  int i = blockIdx.x * blockDim.x + threadIdx.x;
  if (i >= n4) return;
  float4 v = ((const float4*)x)[i];
  ushort4 o;
  o.x = f2b(v.x); o.y = f2b(v.y); o.z = f2b(v.z); o.w = f2b(v.w);
  ((ushort4*)xb)[i] = o;
}

// Build Wcat[512][128] bf16 = rows {Wq*0.125, Wk, Wv, Wskip}; bcat[512] f32
// (bq*0.125, bk, bv, bskip); Wp -> bf16.
__global__ void cvt_w_kernel(const float* __restrict__ Wq, const float* __restrict__ Wk,
                             const float* __restrict__ Wv, const float* __restrict__ Wr,
                             const float* __restrict__ bq, const float* __restrict__ bk,
                             const float* __restrict__ bv, const float* __restrict__ br,
                             const float* __restrict__ Wp,
                             ushort* __restrict__ Wcat, float* __restrict__ bcat,
                             ushort* __restrict__ Wpb) {
  int i = blockIdx.x * blockDim.x + threadIdx.x;
  if (i < 512 * D) {
    int r = i >> 7;
    float v;
    if (r < 128)      v = Wq[i] * 0.125f;
    else if (r < 256) v = Wk[i - 128 * D];
    else if (r < 384) v = Wv[i - 256 * D];
    else              v = Wr[i - 384 * D];
    Wcat[i] = f2b(v);
  }
  if (i < D * D) Wpb[i] = f2b(Wp[i]);
  if (i < 512) {
    float v = (i < 128) ? bq[i] * 0.125f
            : (i < 256) ? bk[i - 128]
            : (i < 384) ? bv[i - 256] : br[i - 384];
    bcat[i] = v;
  }
}

// ======================= MFMA GEMM =======================
// C[M][Ncols] = A[M][128](bf16) @ B[Ncols][128](bf16)^T + bias
// block tile 128x128, 4 waves in 2x2, wave tile 64x64 (4x4 frags of 16x16),
// full K=128 resident in LDS, XOR-swizzled 16B chunks.
// MODE 0: Ncols=512, scatter cols to {q(f32), k->kv(bf16), v->kv(bf16), xr(f32)}
// MODE 1: Ncols=128, write out(f32)
template <int MODE>
__global__ __launch_bounds__(256) void gemm_kernel(
    const ushort* __restrict__ A, const ushort* __restrict__ B,
    const float* __restrict__ bias,
    float* __restrict__ q, ushort* __restrict__ kv, float* __restrict__ xr,
    float* __restrict__ out, int M)
{
  __shared__ __attribute__((aligned(16))) ushort As[128][128];
  __shared__ __attribute__((aligned(16))) ushort Bs[128][128];
  const int tid = threadIdx.x;
  const int rowBase = blockIdx.x * 128;
  const int colBase = blockIdx.y * 128;

#pragma unroll
  for (int it = 0; it < 8; ++it) {
    int i = it * 256 + tid;
    int r = i >> 4, c = i & 15;
    int sw = (c ^ (r & 7)) * 8;
    int gr = rowBase + r;
    uint4 av = make_uint4(0, 0, 0, 0);
    if (gr < M) av = *(const uint4*)(A + (size_t)gr * D + c * 8);
    *(uint4*)(&As[r][sw]) = av;
    uint4 bv4 = *(const uint4*)(B + (size_t)(colBase + r) * D + c * 8);
    *(uint4*)(&Bs[r][sw]) = bv4;
  }
  __syncthreads();

  const int lane = tid & 63;
  const int wave = tid >> 6;
  const int wm = (wave >> 1) * 64;
  const int wn = (wave & 1) * 64;
  const int lrow = lane & 15;
  const int kgrp = lane >> 4;

  f32x4 acc[4][4] = {};
#pragma unroll
  for (int ks = 0; ks < 4; ++ks) {
    int chunk = ks * 4 + kgrp;
    bf16x8 a[4], b[4];
#pragma unroll
    for (int m = 0; m < 4; ++m) {
      int r = wm + m * 16 + lrow;
      a[m] = *(const bf16x8*)&As[r][(chunk ^ (r & 7)) * 8];
    }
#pragma unroll
    for (int n = 0; n < 4; ++n) {
      int r = wn + n * 16 + lrow;
      b[n] = *(const bf16x8*)&Bs[r][(chunk ^ (r & 7)) * 8];
    }
#pragma unroll
    for (int m = 0; m < 4; ++m)
#pragma unroll
      for (int n = 0; n < 4; ++n)
        acc[m][n] = __builtin_amdgcn_mfma_f32_16x16x32_bf16(a[m], b[n], acc[m][n], 0, 0, 0);
  }

  const int orow = (lane >> 4) * 4;
  const int ocol = lane & 15;
#pragma unroll
  for (int m = 0; m < 4; ++m) {
#pragma unroll
    for (int n = 0; n < 4; ++n) {
      int col = colBase + wn + n * 16 + ocol;
      float bi = bias[col];
#pragma unroll
      for (int i = 0; i < 4; ++i) {
        int gr = rowBase + wm + m * 16 + orow + i;
        if (gr >= M) continue;
        float v = acc[m][n][i] + bi;
        if (MODE == 0) {
          int sel = col >> 7, c = col & 127;
          if (sel == 0)      q[(size_t)gr * D + c] = v;
          else if (sel == 1) kv[(size_t)gr * 2 * D + c] = f2b(v);
          else if (sel == 2) kv[(size_t)gr * 2 * D + D + c] = f2b(v);
          else               xr[(size_t)gr * D + c] = v;
        } else {
          out[(size_t)gr * D + col] = v;
        }
      }
    }
  }
}

// ======================= per-node attention =======================
// One wave per node. Lane l owns dims {2l, 2l+1}. Online softmax + beta gate.
// Writes gated output as bf16 to g (input of final projection).
__global__ __launch_bounds__(256) void node_attn_kernel(
    const float* __restrict__ q, const ushort* __restrict__ kv,
    const float* __restrict__ xr, ushort* __restrict__ g,
    const float* __restrict__ edge_attr, const float* __restrict__ We,
    const float* __restrict__ Wb,
    const int* __restrict__ off, const int* __restrict__ ssrc,
    const int* __restrict__ seid, int N)
{
  const int wave = threadIdx.x >> 6;
  const int lane = threadIdx.x & 63;
  const int node = blockIdx.x * 4 + wave;
  if (node >= N) return;

  const int d0 = lane * 2;
  // We is [128][5] row-major; hoist this lane's 10 coefficients
  float we0[EDIM], we1[EDIM];
#pragma unroll
  for (int j = 0; j < EDIM; ++j) {
    we0[j] = We[(size_t)d0 * EDIM + j];
    we1[j] = We[(size_t)(d0 + 1) * EDIM + j];
  }

  const float2 ql = *(const float2*)(q + (size_t)node * D + d0);
  const int beg = off[node], end = off[node + 1];

  float m = -INFINITY, s = 0.f, ox = 0.f, oy = 0.f;

  for (int p = beg; p < end; ++p) {
    int src = ssrc[p];
    int eid = seid[p];
    const float* ea = edge_attr + (size_t)eid * EDIM;
    float e0 = 0.f, e1 = 0.f;
#pragma unroll
    for (int j = 0; j < EDIM; ++j) {
      float a = ea[j];
      e0 += a * we0[j];
      e1 += a * we1[j];
    }
    const ushort* kvp = kv + (size_t)src * 2 * D;
    uint kk = *(const uint*)(kvp + d0);
    uint vv = *(const uint*)(kvp + D + d0);
    float k0 = b2f(kk & 0xffffu) + e0, k1 = b2f(kk >> 16) + e1;
    float v0 = b2f(vv & 0xffffu) + e0, v1 = b2f(vv >> 16) + e1;

    float part = ql.x * k0 + ql.y * k1;
#pragma unroll
    for (int ofs = 1; ofs < 32; ofs <<= 1)
      part += __shfl_xor(part, ofs, 64);
    float alpha = part;                       // per half-wave (per head)

    float nm = fmaxf(m, alpha);
    float scale = __expf(m - nm);
    float pw = __expf(alpha - nm);
    s = s * scale + pw;
    ox = ox * scale + pw * v0;
    oy = oy * scale + pw * v1;
    m = nm;
  }

  float inv = (end > beg) ? (1.f / s) : 0.f;
  ox *= inv; oy *= inv;

  float2 xrl = *(const float2*)(xr + (size_t)node * D + d0);
  float wb1a = Wb[d0] + Wb[256 + d0];
  float wb1b = Wb[d0 + 1] + Wb[256 + d0 + 1];
  float wb2a = Wb[128 + d0] - Wb[256 + d0];
  float wb2b = Wb[128 + d0 + 1] - Wb[256 + d0 + 1];
  float part = ox * wb1a + oy * wb1b + xrl.x * wb2a + xrl.y * wb2b;
#pragma unroll
  for (int ofs = 1; ofs < 64; ofs <<= 1)
    part += __shfl_xor(part, ofs, 64);
  float beta = 1.f / (1.f + __expf(-part));
  float g0 = beta * xrl.x + (1.f - beta) * ox;
  float g1 = beta * xrl.y + (1.f - beta) * oy;
  uint gw = (uint)f2b(g0) | ((uint)f2b(g1) << 16);
  *(uint*)(g + (size_t)node * D + d0) = gw;
}

// ======================= launch =======================

extern "C" void kernel_launch(void* const* d_in, const int* in_sizes, int n_in,
                              void* d_out, int out_size, void* d_ws, size_t ws_size,
                              hipStream_t stream)
{
  const float* x  = (const float*)d_in[0];
  const int*   ei = (const int*)d_in[1];
  const float* ea = (const float*)d_in[2];
  const float* Wq = (const float*)d_in[3];
  const float* bq = (const float*)d_in[4];
  const float* Wk = (const float*)d_in[5];
  const float* bk = (const float*)d_in[6];
  const float* Wv = (const float*)d_in[7];
  const float* bv = (const float*)d_in[8];
  const float* We = (const float*)d_in[9];
  const float* Wr = (const float*)d_in[10];
  const float* br = (const float*)d_in[11];
  const float* Wb = (const float*)d_in[12];
  const float* Wp = (const float*)d_in[13];
  const float* bp = (const float*)d_in[14];

  const int N = in_sizes[0] / D;
  const int E = in_sizes[1] / 2;
  float* out = (float*)d_out;

  char* ws = (char*)d_ws;
  size_t o = 0;
  auto alloc = [&](size_t bytes) -> void* {
    void* p = ws + o;
    o = (o + bytes + 255) & ~(size_t)255;
    return p;
  };
  ushort* xb     = (ushort*)alloc((size_t)N * D * sizeof(ushort));
  float*  q      = (float*)alloc((size_t)N * D * sizeof(float));
  ushort* kv     = (ushort*)alloc((size_t)N * 2 * D * sizeof(ushort));
  float*  xr     = (float*)alloc((size_t)N * D * sizeof(float));
  ushort* g      = (ushort*)alloc((size_t)N * D * sizeof(ushort));
  ushort* Wcat   = (ushort*)alloc((size_t)512 * D * sizeof(ushort));
  float*  bcat   = (float*)alloc(512 * sizeof(float));
  ushort* Wpb    = (ushort*)alloc((size_t)D * D * sizeof(ushort));
  int*    deg    = (int*)alloc((size_t)N * sizeof(int));
  int*    cursor = (int*)alloc((size_t)N * sizeof(int));
  int*    offs   = (int*)alloc((size_t)(N + 1) * sizeof(int));
  int*    ssrc   = (int*)alloc((size_t)E * sizeof(int));
  int*    seid   = (int*)alloc((size_t)E * sizeof(int));

  // sort edges by dst
  zero_int_kernel<<<(N + 255) / 256, 256, 0, stream>>>(deg, N);
  zero_int_kernel<<<(N + 255) / 256, 256, 0, stream>>>(cursor, N);
  hist_kernel<<<(E + 255) / 256, 256, 0, stream>>>(ei, deg, E);
  scan_kernel<<<1, 1024, 0, stream>>>(deg, offs, N);
  scatter_kernel<<<(E + 255) / 256, 256, 0, stream>>>(ei, offs, cursor, ssrc, seid, E);

  // conversions
  cvt_x_kernel<<<(N * D / 4 + 255) / 256, 256, 0, stream>>>(x, xb, N * D / 4);
  cvt_w_kernel<<<(512 * D + 255) / 256, 256, 0, stream>>>(Wq, Wk, Wv, Wr, bq, bk, bv, br,
                                                          Wp, Wcat, bcat, Wpb);

  // fused projections via MFMA: [q*1/8 | k | v | xr]
  dim3 g0((N + 127) / 128, 4);
  gemm_kernel<0><<<g0, 256, 0, stream>>>(xb, Wcat, bcat, q, kv, xr, nullptr, N);

  // per-node online-softmax attention + beta gate -> g (bf16)
  node_attn_kernel<<<(N + 3) / 4, 256, 0, stream>>>(q, kv, xr, g, ea, We, Wb,
                                                    offs, ssrc, seid, N);

  // final projection via MFMA
  dim3 g1((N + 127) / 128, 1);
  gemm_kernel<1><<<g1, 256, 0, stream>>>(g, Wpb, bp, nullptr, nullptr, nullptr, out, N);
}

// Round 3
// 255.970 us; speedup vs baseline: 2.3941x; 1.3659x over previous
//
#include <hip/hip_runtime.h>
#include <stdint.h>
#include <math.h>

#define D 128
#define EDIM 5

typedef __attribute__((ext_vector_type(8))) short bf16x8;
typedef __attribute__((ext_vector_type(4))) float f32x4;

__device__ __forceinline__ ushort f2b(float f) {
  union { float f; uint u; } v; v.f = f;
  uint u = v.u;
  return (ushort)((u + 0x7fff + ((u >> 16) & 1)) >> 16);   // RNE
}
__device__ __forceinline__ float blo(uint u) {
  union { uint u; float f; } v; v.u = u << 16; return v.f;
}
__device__ __forceinline__ float bhi(uint u) {
  union { uint u; float f; } v; v.u = u & 0xffff0000u; return v.f;
}

// ======================= utility kernels =======================

__global__ void zero_int_kernel(int* __restrict__ p, int n) {
  int i = blockIdx.x * blockDim.x + threadIdx.x;
  if (i < n) p[i] = 0;
}

__global__ void hist_kernel(const int* __restrict__ ei, int* __restrict__ deg, int E) {
  int e = blockIdx.x * blockDim.x + threadIdx.x;
  if (e < E) atomicAdd(&deg[ei[(size_t)E + e]], 1);
}

// ---- hierarchical exclusive scan over deg[N] -> off[N+1] ----
__global__ __launch_bounds__(256) void scan_p1(const int* __restrict__ deg,
                                               int* __restrict__ off,
                                               int* __restrict__ blockSum, int n4) {
  __shared__ int waveTot[4];
  int idx = blockIdx.x * 256 + threadIdx.x;
  int4 v = make_int4(0, 0, 0, 0);
  if (idx < n4) v = ((const int4*)deg)[idx];
  int c0 = v.x, c1 = c0 + v.y, c2 = c1 + v.z, c3 = c2 + v.w;
  int tot = c3;
  int lane = threadIdx.x & 63, w = threadIdx.x >> 6;
  int incl = tot;
#pragma unroll
  for (int ofs = 1; ofs < 64; ofs <<= 1) {
    int t = __shfl_up(incl, ofs, 64);
    if (lane >= ofs) incl += t;
  }
  if (lane == 63) waveTot[w] = incl;
  __syncthreads();
  int wbase = 0;
  for (int i = 0; i < w; ++i) wbase += waveTot[i];
  int excl = wbase + incl - tot;
  if (idx < n4) {
    int4 o;
    o.x = excl; o.y = excl + c0; o.z = excl + c1; o.w = excl + c2;
    ((int4*)off)[idx] = o;
  }
  if (threadIdx.x == 255) blockSum[blockIdx.x] = wbase + incl;
}

__global__ void scan_p2(const int* __restrict__ blockSum, int* __restrict__ blockBase,
                        int* __restrict__ off_last, int nb) {
  int lane = threadIdx.x;            // 64 threads, nb <= 64
  int v = (lane < nb) ? blockSum[lane] : 0;
  int incl = v;
#pragma unroll
  for (int ofs = 1; ofs < 64; ofs <<= 1) {
    int t = __shfl_up(incl, ofs, 64);
    if (lane >= ofs) incl += t;
  }
  if (lane < nb) blockBase[lane] = incl - v;
  if (lane == 63) *off_last = incl;
}

__global__ __launch_bounds__(256) void scan_p3(int* __restrict__ off,
                                               const int* __restrict__ blockBase, int n4) {
  int idx = blockIdx.x * 256 + threadIdx.x;
  if (idx >= n4) return;
  int b = blockBase[blockIdx.x];
  int4 v = ((int4*)off)[idx];
  v.x += b; v.y += b; v.z += b; v.w += b;
  ((int4*)off)[idx] = v;
}

// sort edges by dst; also gather edge_attr into sorted order as bf16x8
__global__ void scatter_kernel(const int* __restrict__ ei, const float* __restrict__ ea,
                               const int* __restrict__ off, int* __restrict__ cursor,
                               int* __restrict__ ssrc, uint4* __restrict__ easrt, int E) {
  int e = blockIdx.x * blockDim.x + threadIdx.x;
  if (e >= E) return;
  int dst = ei[(size_t)E + e];
  int pos = off[dst] + atomicAdd(&cursor[dst], 1);
  ssrc[pos] = ei[e];
  const float* p = ea + (size_t)e * EDIM;
  uint e0 = f2b(p[0]), e1 = f2b(p[1]), e2 = f2b(p[2]), e3 = f2b(p[3]), e4 = f2b(p[4]);
  easrt[pos] = make_uint4(e0 | (e1 << 16), e2 | (e3 << 16), e4, 0);
}

// ======================= conversions =======================

__global__ void cvt_x_kernel(const float* __restrict__ x, ushort* __restrict__ xb, int n4) {
  int i = blockIdx.x * blockDim.x + threadIdx.x;
  if (i >= n4) return;
  float4 v = ((const float4*)x)[i];
  ushort4 o;
  o.x = f2b(v.x); o.y = f2b(v.y); o.z = f2b(v.z); o.w = f2b(v.w);
  ((ushort4*)xb)[i] = o;
}

__global__ void cvt_w_kernel(const float* __restrict__ Wq, const float* __restrict__ Wk,
                             const float* __restrict__ Wv, const float* __restrict__ Wr,
                             const float* __restrict__ bq, const float* __restrict__ bk,
                             const float* __restrict__ bv, const float* __restrict__ br,
                             const float* __restrict__ Wp,
                             ushort* __restrict__ Wcat, float* __restrict__ bcat,
                             ushort* __restrict__ Wpb) {
  int i = blockIdx.x * blockDim.x + threadIdx.x;
  if (i < 512 * D) {
    int r = i >> 7;
    float v;
    if (r < 128)      v = Wq[i] * 0.125f;
    else if (r < 256) v = Wk[i - 128 * D];
    else if (r < 384) v = Wv[i - 256 * D];
    else              v = Wr[i - 384 * D];
    Wcat[i] = f2b(v);
  }
  if (i < D * D) Wpb[i] = f2b(Wp[i]);
  if (i < 512) {
    float v = (i < 128) ? bq[i] * 0.125f
            : (i < 256) ? bk[i - 128]
            : (i < 384) ? bv[i - 256] : br[i - 384];
    bcat[i] = v;
  }
}

// ======================= MFMA GEMM =======================
template <int MODE>
__global__ __launch_bounds__(256) void gemm_kernel(
    const ushort* __restrict__ A, const ushort* __restrict__ B,
    const float* __restrict__ bias,
    float* __restrict__ q, ushort* __restrict__ kv, float* __restrict__ xr,
    float* __restrict__ out, int M)
{
  __shared__ __attribute__((aligned(16))) ushort As[128][128];
  __shared__ __attribute__((aligned(16))) ushort Bs[128][128];
  const int tid = threadIdx.x;
  const int rowBase = blockIdx.x * 128;
  const int colBase = blockIdx.y * 128;

#pragma unroll
  for (int it = 0; it < 8; ++it) {
    int i = it * 256 + tid;
    int r = i >> 4, c = i & 15;
    int sw = (c ^ (r & 7)) * 8;
    int gr = rowBase + r;
    uint4 av = make_uint4(0, 0, 0, 0);
    if (gr < M) av = *(const uint4*)(A + (size_t)gr * D + c * 8);
    *(uint4*)(&As[r][sw]) = av;
    uint4 bv4 = *(const uint4*)(B + (size_t)(colBase + r) * D + c * 8);
    *(uint4*)(&Bs[r][sw]) = bv4;
  }
  __syncthreads();

  const int lane = tid & 63;
  const int wave = tid >> 6;
  const int wm = (wave >> 1) * 64;
  const int wn = (wave & 1) * 64;
  const int lrow = lane & 15;
  const int kgrp = lane >> 4;

  f32x4 acc[4][4] = {};
#pragma unroll
  for (int ks = 0; ks < 4; ++ks) {
    int chunk = ks * 4 + kgrp;
    bf16x8 a[4], b[4];
#pragma unroll
    for (int m = 0; m < 4; ++m) {
      int r = wm + m * 16 + lrow;
      a[m] = *(const bf16x8*)&As[r][(chunk ^ (r & 7)) * 8];
    }
#pragma unroll
    for (int n = 0; n < 4; ++n) {
      int r = wn + n * 16 + lrow;
      b[n] = *(const bf16x8*)&Bs[r][(chunk ^ (r & 7)) * 8];
    }
#pragma unroll
    for (int m = 0; m < 4; ++m)
#pragma unroll
      for (int n = 0; n < 4; ++n)
        acc[m][n] = __builtin_amdgcn_mfma_f32_16x16x32_bf16(a[m], b[n], acc[m][n], 0, 0, 0);
  }

  const int orow = (lane >> 4) * 4;
  const int ocol = lane & 15;
#pragma unroll
  for (int m = 0; m < 4; ++m) {
#pragma unroll
    for (int n = 0; n < 4; ++n) {
      int col = colBase + wn + n * 16 + ocol;
      float bi = bias[col];
#pragma unroll
      for (int i = 0; i < 4; ++i) {
        int gr = rowBase + wm + m * 16 + orow + i;
        if (gr >= M) continue;
        float v = acc[m][n][i] + bi;
        if (MODE == 0) {
          int sel = col >> 7, c = col & 127;
          if (sel == 0)      q[(size_t)gr * D + c] = v;
          else if (sel == 1) kv[(size_t)gr * 2 * D + c] = f2b(v);
          else if (sel == 2) kv[(size_t)gr * 2 * D + D + c] = f2b(v);
          else               xr[(size_t)gr * D + c] = v;
        } else {
          out[(size_t)gr * D + col] = v;
        }
      }
    }
  }
}

// ======================= per-node attention v2 =======================
// One wave per node. Lane = (group g = lane>>4, i = lane&15).
// Group g processes edge slot p+g (4 edges in flight); lane i owns dims 8i..8i+7
// (i<8 -> head 0, i>=8 -> head 1). Per-group online softmax (m,s,o[8],wea[5]),
// merged across groups at the end. Edge features factored:
//   alpha = q~.k[src] + (q~^T We).ea ;  O = sum w v[src] + We @ (sum w ea)
__global__ __launch_bounds__(256) void node_attn_kernel(
    const float* __restrict__ q, const ushort* __restrict__ kv,
    const float* __restrict__ xr, ushort* __restrict__ g,
    const uint4* __restrict__ easrt, const float* __restrict__ We,
    const float* __restrict__ Wb,
    const int* __restrict__ off, const int* __restrict__ ssrc, int N)
{
  const int wid = threadIdx.x >> 6;
  const int lane = threadIdx.x & 63;
  const int node = blockIdx.x * 4 + wid;
  if (node >= N) return;
  const int grp = lane >> 4;
  const int i = lane & 15;
  const int di = i * 8;

  // q row (f32, pre-scaled by 1/8): dims di..di+7
  float qr[8];
  {
    float4 a = *(const float4*)(q + (size_t)node * D + di);
    float4 b = *(const float4*)(q + (size_t)node * D + di + 4);
    qr[0] = a.x; qr[1] = a.y; qr[2] = a.z; qr[3] = a.w;
    qr[4] = b.x; qr[5] = b.y; qr[6] = b.z; qr[7] = b.w;
  }

  // qwe[j] = sum over this head's 64 dims of q~[d]*We[d][j]
  float qwe[5];
  {
    const float* wp = We + (size_t)di * EDIM;
    float4 w[10];
#pragma unroll
    for (int t = 0; t < 10; ++t) w[t] = *(const float4*)(wp + 4 * t);
#pragma unroll
    for (int j = 0; j < 5; ++j) {
      float s = 0.f;
#pragma unroll
      for (int r = 0; r < 8; ++r) {
        int idx = r * 5 + j;
        s += qr[r] * ((const float*)&w[idx >> 2])[idx & 3];
      }
      qwe[j] = s;
    }
#pragma unroll
    for (int ofs = 1; ofs < 8; ofs <<= 1)
#pragma unroll
      for (int j = 0; j < 5; ++j) qwe[j] += __shfl_xor(qwe[j], ofs, 64);
  }

  const int beg = off[node], end = off[node + 1];
  float m = -INFINITY, s = 0.f;
  float o[8] = {0.f, 0.f, 0.f, 0.f, 0.f, 0.f, 0.f, 0.f};
  float wea[5] = {0.f, 0.f, 0.f, 0.f, 0.f};

  for (int pb = beg; pb < end; pb += 4) {
    int p = pb + grp;
    bool valid = p < end;
    int pl = valid ? p : beg;
    int src = ssrc[pl];
    uint4 eau = easrt[pl];
    float ea0 = blo(eau.x), ea1 = bhi(eau.x);
    float ea2 = blo(eau.y), ea3 = bhi(eau.y);
    float ea4 = blo(eau.z);

    const ushort* kp = kv + (size_t)src * 2 * D;
    uint4 ku = *(const uint4*)(kp + di);
    uint4 vu = *(const uint4*)(kp + D + di);

    float part = qr[0] * blo(ku.x) + qr[1] * bhi(ku.x)
               + qr[2] * blo(ku.y) + qr[3] * bhi(ku.y)
               + qr[4] * blo(ku.z) + qr[5] * bhi(ku.z)
               + qr[6] * blo(ku.w) + qr[7] * bhi(ku.w);
#pragma unroll
    for (int ofs = 1; ofs < 8; ofs <<= 1) part += __shfl_xor(part, ofs, 64);
    float eadot = qwe[0] * ea0 + qwe[1] * ea1 + qwe[2] * ea2 + qwe[3] * ea3 + qwe[4] * ea4;
    float alpha = valid ? (part + eadot) : -INFINITY;

    float nm = fmaxf(m, alpha);
    float scale = (m > -1e30f) ? __expf(m - nm) : 0.f;
    float pw = (alpha > -1e30f) ? __expf(alpha - nm) : 0.f;
    m = nm;
    s = s * scale + pw;
    o[0] = o[0] * scale + pw * blo(vu.x);
    o[1] = o[1] * scale + pw * bhi(vu.x);
    o[2] = o[2] * scale + pw * blo(vu.y);
    o[3] = o[3] * scale + pw * bhi(vu.y);
    o[4] = o[4] * scale + pw * blo(vu.z);
    o[5] = o[5] * scale + pw * bhi(vu.z);
    o[6] = o[6] * scale + pw * blo(vu.w);
    o[7] = o[7] * scale + pw * bhi(vu.w);
    wea[0] = wea[0] * scale + pw * ea0;
    wea[1] = wea[1] * scale + pw * ea1;
    wea[2] = wea[2] * scale + pw * ea2;
    wea[3] = wea[3] * scale + pw * ea3;
    wea[4] = wea[4] * scale + pw * ea4;
  }

  // merge the 4 groups (lane bits 4,5)
#pragma unroll
  for (int ofs = 16; ofs < 64; ofs <<= 1) {
    float m2 = __shfl_xor(m, ofs, 64);
    float s2 = __shfl_xor(s, ofs, 64);
    float o2[8], w2[5];
#pragma unroll
    for (int j = 0; j < 8; ++j) o2[j] = __shfl_xor(o[j], ofs, 64);
#pragma unroll
    for (int j = 0; j < 5; ++j) w2[j] = __shfl_xor(wea[j], ofs, 64);
    float nm = fmaxf(m, m2);
    float e1 = (m > -1e30f) ? __expf(m - nm) : 0.f;
    float e2 = (m2 > -1e30f) ? __expf(m2 - nm) : 0.f;
    s = s * e1 + s2 * e2;
#pragma unroll
    for (int j = 0; j < 8; ++j) o[j] = o[j] * e1 + o2[j] * e2;
#pragma unroll
    for (int j = 0; j < 5; ++j) wea[j] = wea[j] * e1 + w2[j] * e2;
    m = nm;
  }

  float inv = (s > 0.f) ? (1.f / s) : 0.f;
#pragma unroll
  for (int j = 0; j < 8; ++j) o[j] *= inv;
#pragma unroll
  for (int j = 0; j < 5; ++j) wea[j] *= inv;

  // O += We @ wea for this lane's 8 dims
  {
    const float* wp = We + (size_t)di * EDIM;
    float4 w[10];
#pragma unroll
    for (int t = 0; t < 10; ++t) w[t] = *(const float4*)(wp + 4 * t);
#pragma unroll
    for (int r = 0; r < 8; ++r)
#pragma unroll
      for (int j = 0; j < 5; ++j) {
        int idx = r * 5 + j;
        o[r] += wea[j] * ((const float*)&w[idx >> 2])[idx & 3];
      }
  }

  // beta gate
  float xrv[8];
  {
    float4 a = *(const float4*)(xr + (size_t)node * D + di);
    float4 b = *(const float4*)(xr + (size_t)node * D + di + 4);
    xrv[0] = a.x; xrv[1] = a.y; xrv[2] = a.z; xrv[3] = a.w;
    xrv[4] = b.x; xrv[5] = b.y; xrv[6] = b.z; xrv[7] = b.w;
  }
  float part = 0.f;
#pragma unroll
  for (int r = 0; r < 8; ++r) {
    float w1 = Wb[di + r] + Wb[256 + di + r];
    float w2 = Wb[128 + di + r] - Wb[256 + di + r];
    part += o[r] * w1 + xrv[r] * w2;
  }
#pragma unroll
  for (int ofs = 1; ofs < 16; ofs <<= 1) part += __shfl_xor(part, ofs, 64);
  float beta = 1.f / (1.f + __expf(-part));

  if (grp == 0) {
    uint pk[4];
#pragma unroll
    for (int r = 0; r < 4; ++r) {
      float g0 = beta * xrv[2 * r] + (1.f - beta) * o[2 * r];
      float g1 = beta * xrv[2 * r + 1] + (1.f - beta) * o[2 * r + 1];
      pk[r] = (uint)f2b(g0) | ((uint)f2b(g1) << 16);
    }
    *(uint4*)(g + (size_t)node * D + di) = make_uint4(pk[0], pk[1], pk[2], pk[3]);
  }
}

// ======================= launch =======================

extern "C" void kernel_launch(void* const* d_in, const int* in_sizes, int n_in,
                              void* d_out, int out_size, void* d_ws, size_t ws_size,
                              hipStream_t stream)
{
  const float* x  = (const float*)d_in[0];
  const int*   ei = (const int*)d_in[1];
  const float* ea = (const float*)d_in[2];
  const float* Wq = (const float*)d_in[3];
  const float* bq = (const float*)d_in[4];
  const float* Wk = (const float*)d_in[5];
  const float* bk = (const float*)d_in[6];
  const float* Wv = (const float*)d_in[7];
  const float* bv = (const float*)d_in[8];
  const float* We = (const float*)d_in[9];
  const float* Wr = (const float*)d_in[10];
  const float* br = (const float*)d_in[11];
  const float* Wb = (const float*)d_in[12];
  const float* Wp = (const float*)d_in[13];
  const float* bp = (const float*)d_in[14];

  const int N = in_sizes[0] / D;
  const int E = in_sizes[1] / 2;
  float* out = (float*)d_out;

  char* ws = (char*)d_ws;
  size_t o = 0;
  auto alloc = [&](size_t bytes) -> void* {
    void* p = ws + o;
    o = (o + bytes + 255) & ~(size_t)255;
    return p;
  };
  ushort* xb     = (ushort*)alloc((size_t)N * D * sizeof(ushort));
  float*  q      = (float*)alloc((size_t)N * D * sizeof(float));
  ushort* kv     = (ushort*)alloc((size_t)N * 2 * D * sizeof(ushort));
  float*  xr     = (float*)alloc((size_t)N * D * sizeof(float));
  ushort* g      = (ushort*)alloc((size_t)N * D * sizeof(ushort));
  ushort* Wcat   = (ushort*)alloc((size_t)512 * D * sizeof(ushort));
  float*  bcat   = (float*)alloc(512 * sizeof(float));
  ushort* Wpb    = (ushort*)alloc((size_t)D * D * sizeof(ushort));
  int*    deg    = (int*)alloc((size_t)N * sizeof(int));
  int*    cursor = (int*)alloc((size_t)N * sizeof(int));
  int*    offs   = (int*)alloc((size_t)(N + 1) * sizeof(int));
  int*    ssrc   = (int*)alloc((size_t)E * sizeof(int));
  uint4*  easrt  = (uint4*)alloc((size_t)E * sizeof(uint4));
  int*    bsum   = (int*)alloc(64 * sizeof(int));
  int*    bbase  = (int*)alloc(64 * sizeof(int));

  const int n4 = N / 4;                    // N divisible by 4
  const int nb = (n4 + 255) / 256;         // scan blocks (<= 64)

  zero_int_kernel<<<(N + 255) / 256, 256, 0, stream>>>(deg, N);
  zero_int_kernel<<<(N + 255) / 256, 256, 0, stream>>>(cursor, N);
  hist_kernel<<<(E + 255) / 256, 256, 0, stream>>>(ei, deg, E);
  scan_p1<<<nb, 256, 0, stream>>>(deg, offs, bsum, n4);
  scan_p2<<<1, 64, 0, stream>>>(bsum, bbase, offs + N, nb);
  scan_p3<<<nb, 256, 0, stream>>>(offs, bbase, n4);
  scatter_kernel<<<(E + 255) / 256, 256, 0, stream>>>(ei, ea, offs, cursor, ssrc, easrt, E);

  cvt_x_kernel<<<(N * D / 4 + 255) / 256, 256, 0, stream>>>(x, xb, N * D / 4);
  cvt_w_kernel<<<(512 * D + 255) / 256, 256, 0, stream>>>(Wq, Wk, Wv, Wr, bq, bk, bv, br,
                                                          Wp, Wcat, bcat, Wpb);

  dim3 g0((N + 127) / 128, 4);
  gemm_kernel<0><<<g0, 256, 0, stream>>>(xb, Wcat, bcat, q, kv, xr, nullptr, N);

  node_attn_kernel<<<(N + 3) / 4, 256, 0, stream>>>(q, kv, xr, g, easrt, We, Wb,
                                                    offs, ssrc, N);

  dim3 g1((N + 127) / 128, 1);
  gemm_kernel<1><<<g1, 256, 0, stream>>>(g, Wpb, bp, nullptr, nullptr, nullptr, out, N);
}

// Round 4
// 241.193 us; speedup vs baseline: 2.5408x; 1.0613x over previous
//
#include <hip/hip_runtime.h>
#include <stdint.h>
#include <math.h>

#define D 128
#define EDIM 5

typedef __attribute__((ext_vector_type(8))) short bf16x8;
typedef __attribute__((ext_vector_type(4))) float f32x4;

__device__ __forceinline__ ushort f2b(float f) {
  union { float f; uint u; } v; v.f = f;
  uint u = v.u;
  return (ushort)((u + 0x7fff + ((u >> 16) & 1)) >> 16);   // RNE
}
__device__ __forceinline__ float blo(uint u) {
  union { uint u; float f; } v; v.u = u << 16; return v.f;
}
__device__ __forceinline__ float bhi(uint u) {
  union { uint u; float f; } v; v.u = u & 0xffff0000u; return v.f;
}

// ======================= utility kernels =======================

__global__ void zero_int_kernel(int* __restrict__ p, int n) {
  int i = blockIdx.x * blockDim.x + threadIdx.x;
  if (i < n) p[i] = 0;
}

__global__ void hist_kernel(const int* __restrict__ ei, int* __restrict__ deg, int E) {
  int e = blockIdx.x * blockDim.x + threadIdx.x;
  if (e < E) atomicAdd(&deg[ei[(size_t)E + e]], 1);
}

// ---- hierarchical exclusive scan over deg[N] -> off[N+1] ----
__global__ __launch_bounds__(256) void scan_p1(const int* __restrict__ deg,
                                               int* __restrict__ off,
                                               int* __restrict__ blockSum, int n4) {
  __shared__ int waveTot[4];
  int idx = blockIdx.x * 256 + threadIdx.x;
  int4 v = make_int4(0, 0, 0, 0);
  if (idx < n4) v = ((const int4*)deg)[idx];
  int c0 = v.x, c1 = c0 + v.y, c2 = c1 + v.z, c3 = c2 + v.w;
  int tot = c3;
  int lane = threadIdx.x & 63, w = threadIdx.x >> 6;
  int incl = tot;
#pragma unroll
  for (int ofs = 1; ofs < 64; ofs <<= 1) {
    int t = __shfl_up(incl, ofs, 64);
    if (lane >= ofs) incl += t;
  }
  if (lane == 63) waveTot[w] = incl;
  __syncthreads();
  int wbase = 0;
  for (int i = 0; i < w; ++i) wbase += waveTot[i];
  int excl = wbase + incl - tot;
  if (idx < n4) {
    int4 o;
    o.x = excl; o.y = excl + c0; o.z = excl + c1; o.w = excl + c2;
    ((int4*)off)[idx] = o;
  }
  if (threadIdx.x == 255) blockSum[blockIdx.x] = wbase + incl;
}

__global__ void scan_p2(const int* __restrict__ blockSum, int* __restrict__ blockBase,
                        int* __restrict__ off_last, int nb) {
  int lane = threadIdx.x;            // 64 threads, nb <= 64
  int v = (lane < nb) ? blockSum[lane] : 0;
  int incl = v;
#pragma unroll
  for (int ofs = 1; ofs < 64; ofs <<= 1) {
    int t = __shfl_up(incl, ofs, 64);
    if (lane >= ofs) incl += t;
  }
  if (lane < nb) blockBase[lane] = incl - v;
  if (lane == 63) *off_last = incl;
}

// also zeroes cursor (saves a launch)
__global__ __launch_bounds__(256) void scan_p3(int* __restrict__ off,
                                               const int* __restrict__ blockBase,
                                               int* __restrict__ cursor, int n4) {
  int idx = blockIdx.x * 256 + threadIdx.x;
  if (idx >= n4) return;
  int b = blockBase[blockIdx.x];
  int4 v = ((int4*)off)[idx];
  v.x += b; v.y += b; v.z += b; v.w += b;
  ((int4*)off)[idx] = v;
  ((int4*)cursor)[idx] = make_int4(0, 0, 0, 0);
}

// sort edges by dst; gather edge_attr into sorted order as packed bf16
__global__ void scatter_kernel(const int* __restrict__ ei, const float* __restrict__ ea,
                               const int* __restrict__ off, int* __restrict__ cursor,
                               int* __restrict__ ssrc, uint4* __restrict__ easrt, int E) {
  int e = blockIdx.x * blockDim.x + threadIdx.x;
  if (e >= E) return;
  int dst = ei[(size_t)E + e];
  int pos = off[dst] + atomicAdd(&cursor[dst], 1);
  ssrc[pos] = ei[e];
  const float* p = ea + (size_t)e * EDIM;
  uint e0 = f2b(p[0]), e1 = f2b(p[1]), e2 = f2b(p[2]), e3 = f2b(p[3]), e4 = f2b(p[4]);
  easrt[pos] = make_uint4(e0 | (e1 << 16), e2 | (e3 << 16), e4, 0);
}

// ======================= weight prep =======================
// Wcat[640][128] bf16: rows 0-127 Wq*0.125, 128-255 Wk, 256-383 Wv, 384-511 Wskip,
// 512-639: composite rows for qwe (row 512+h*8+j = sum_{d in head h} We[d][j]*0.125*Wq[d][:]),
// zeros elsewhere. bcat[640] f32 similarly (+ composite bias from bq).
__global__ void cvt_w_kernel(const float* __restrict__ Wq, const float* __restrict__ Wk,
                             const float* __restrict__ Wv, const float* __restrict__ Wr,
                             const float* __restrict__ bq, const float* __restrict__ bk,
                             const float* __restrict__ bv, const float* __restrict__ br,
                             const float* __restrict__ We, const float* __restrict__ Wp,
                             ushort* __restrict__ Wcat, float* __restrict__ bcat,
                             ushort* __restrict__ Wpb) {
  int i = blockIdx.x * blockDim.x + threadIdx.x;
  if (i < 512 * D) {
    int r = i >> 7;
    float v;
    if (r < 128)      v = Wq[i] * 0.125f;
    else if (r < 256) v = Wk[i - 128 * D];
    else if (r < 384) v = Wv[i - 256 * D];
    else              v = Wr[i - 384 * D];
    Wcat[i] = f2b(v);
  } else if (i < 512 * D + 128 * D) {
    int ie = i - 512 * D;
    int r = ie >> 7, c = ie & 127;          // Wcat row 512+r
    int h = r >> 3, j = r & 7;
    float v = 0.f;
    if (h < 2 && j < 5) {
      for (int d = 0; d < 64; ++d) {
        int dd = h * 64 + d;
        v += We[(size_t)dd * EDIM + j] * 0.125f * Wq[(size_t)dd * D + c];
      }
    }
    Wcat[(size_t)(512 + r) * D + c] = f2b(v);
  }
  if (i < D * D) Wpb[i] = f2b(Wp[i]);
  if (i < 512) {
    float v = (i < 128) ? bq[i] * 0.125f
            : (i < 256) ? bk[i - 128]
            : (i < 384) ? bv[i - 256] : br[i - 384];
    bcat[i] = v;
  } else if (i < 640) {
    int t = i - 512;
    int h = t >> 3, j = t & 7;
    float v = 0.f;
    if (h < 2 && j < 5) {
      for (int d = 0; d < 64; ++d) {
        int dd = h * 64 + d;
        v += bq[dd] * 0.125f * We[(size_t)dd * EDIM + j];
      }
    }
    bcat[i] = v;
  }
}

// ======================= fused projection GEMM =======================
// BM=64 row tile, inner loop over 5 col-blocks of 128 (B stays L2-hot, A read once).
// A = x (f32, converted to bf16 during LDS staging). Outputs:
// cols 0-127 -> q (bf16), 128-255 -> kv.K (bf16), 256-383 -> kv.V (bf16),
// 384-511 -> xr (bf16), 512-527 -> qwe (f32).
__global__ __launch_bounds__(256) void proj_gemm_kernel(
    const float* __restrict__ x, const ushort* __restrict__ Wcat,
    const float* __restrict__ bcat,
    ushort* __restrict__ q, ushort* __restrict__ kv, ushort* __restrict__ xr,
    float* __restrict__ qwe, int M)
{
  __shared__ __attribute__((aligned(16))) ushort As[64][128];
  __shared__ __attribute__((aligned(16))) ushort Bs[128][128];
  const int tid = threadIdx.x;
  const int rowBase = blockIdx.x * 64;

  // stage A with fused f32->bf16 convert
#pragma unroll
  for (int it = 0; it < 4; ++it) {
    int i = it * 256 + tid;
    int r = i >> 4, c = i & 15;
    int gr = rowBase + r;
    float4 a0 = make_float4(0.f, 0.f, 0.f, 0.f), a1 = a0;
    if (gr < M) {
      a0 = *(const float4*)(x + (size_t)gr * D + c * 8);
      a1 = *(const float4*)(x + (size_t)gr * D + c * 8 + 4);
    }
    uint4 w;
    w.x = (uint)f2b(a0.x) | ((uint)f2b(a0.y) << 16);
    w.y = (uint)f2b(a0.z) | ((uint)f2b(a0.w) << 16);
    w.z = (uint)f2b(a1.x) | ((uint)f2b(a1.y) << 16);
    w.w = (uint)f2b(a1.z) | ((uint)f2b(a1.w) << 16);
    *(uint4*)(&As[r][(c ^ (r & 7)) * 8]) = w;
  }

  const int lane = tid & 63;
  const int wave = tid >> 6;
  const int wm = (wave >> 1) * 32;
  const int wn = (wave & 1) * 64;
  const int lrow = lane & 15;
  const int kgrp = lane >> 4;
  const int orow = (lane >> 4) * 4;
  const int ocol = lane & 15;

  for (int cb = 0; cb < 5; ++cb) {
    // stage B block (Wcat rows cb*128 .. +127)
#pragma unroll
    for (int it = 0; it < 8; ++it) {
      int i = it * 256 + tid;
      int r = i >> 4, c = i & 15;
      uint4 bv4 = *(const uint4*)(Wcat + (size_t)(cb * 128 + r) * D + c * 8);
      *(uint4*)(&Bs[r][(c ^ (r & 7)) * 8]) = bv4;
    }
    __syncthreads();

    f32x4 acc[2][4] = {};
#pragma unroll
    for (int ks = 0; ks < 4; ++ks) {
      int chunk = ks * 4 + kgrp;
      bf16x8 a[2], b[4];
#pragma unroll
      for (int m = 0; m < 2; ++m) {
        int r = wm + m * 16 + lrow;
        a[m] = *(const bf16x8*)&As[r][(chunk ^ (r & 7)) * 8];
      }
#pragma unroll
      for (int n = 0; n < 4; ++n) {
        int r = wn + n * 16 + lrow;
        b[n] = *(const bf16x8*)&Bs[r][(chunk ^ (r & 7)) * 8];
      }
#pragma unroll
      for (int m = 0; m < 2; ++m)
#pragma unroll
        for (int n = 0; n < 4; ++n)
          acc[m][n] = __builtin_amdgcn_mfma_f32_16x16x32_bf16(a[m], b[n], acc[m][n], 0, 0, 0);
    }

#pragma unroll
    for (int m = 0; m < 2; ++m) {
#pragma unroll
      for (int n = 0; n < 4; ++n) {
        int col = cb * 128 + wn + n * 16 + ocol;
        float bi = bcat[col];
        int sel = col >> 7, c = col & 127;
#pragma unroll
        for (int ii = 0; ii < 4; ++ii) {
          int gr = rowBase + wm + m * 16 + orow + ii;
          if (gr >= M) continue;
          float v = acc[m][n][ii] + bi;
          if (sel == 0)      q[(size_t)gr * D + c] = f2b(v);
          else if (sel == 1) kv[(size_t)gr * 2 * D + c] = f2b(v);
          else if (sel == 2) kv[(size_t)gr * 2 * D + D + c] = f2b(v);
          else if (sel == 3) xr[(size_t)gr * D + c] = f2b(v);
          else if (c < 16)   qwe[(size_t)gr * 16 + c] = v;
        }
      }
    }
    __syncthreads();
  }
}

// ======================= output projection GEMM =======================
__global__ __launch_bounds__(256) void out_gemm_kernel(
    const ushort* __restrict__ g, const ushort* __restrict__ Wpb,
    const float* __restrict__ bp, float* __restrict__ out, int M)
{
  __shared__ __attribute__((aligned(16))) ushort As[64][128];
  __shared__ __attribute__((aligned(16))) ushort Bs[128][128];
  const int tid = threadIdx.x;
  const int rowBase = blockIdx.x * 64;

#pragma unroll
  for (int it = 0; it < 4; ++it) {
    int i = it * 256 + tid;
    int r = i >> 4, c = i & 15;
    int gr = rowBase + r;
    uint4 av = make_uint4(0, 0, 0, 0);
    if (gr < M) av = *(const uint4*)(g + (size_t)gr * D + c * 8);
    *(uint4*)(&As[r][(c ^ (r & 7)) * 8]) = av;
  }
#pragma unroll
  for (int it = 0; it < 8; ++it) {
    int i = it * 256 + tid;
    int r = i >> 4, c = i & 15;
    uint4 bv4 = *(const uint4*)(Wpb + (size_t)r * D + c * 8);
    *(uint4*)(&Bs[r][(c ^ (r & 7)) * 8]) = bv4;
  }
  __syncthreads();

  const int lane = tid & 63;
  const int wave = tid >> 6;
  const int wm = (wave >> 1) * 32;
  const int wn = (wave & 1) * 64;
  const int lrow = lane & 15;
  const int kgrp = lane >> 4;

  f32x4 acc[2][4] = {};
#pragma unroll
  for (int ks = 0; ks < 4; ++ks) {
    int chunk = ks * 4 + kgrp;
    bf16x8 a[2], b[4];
#pragma unroll
    for (int m = 0; m < 2; ++m) {
      int r = wm + m * 16 + lrow;
      a[m] = *(const bf16x8*)&As[r][(chunk ^ (r & 7)) * 8];
    }
#pragma unroll
    for (int n = 0; n < 4; ++n) {
      int r = wn + n * 16 + lrow;
      b[n] = *(const bf16x8*)&Bs[r][(chunk ^ (r & 7)) * 8];
    }
#pragma unroll
    for (int m = 0; m < 2; ++m)
#pragma unroll
      for (int n = 0; n < 4; ++n)
        acc[m][n] = __builtin_amdgcn_mfma_f32_16x16x32_bf16(a[m], b[n], acc[m][n], 0, 0, 0);
  }

  const int orow = (lane >> 4) * 4;
  const int ocol = lane & 15;
#pragma unroll
  for (int m = 0; m < 2; ++m) {
#pragma unroll
    for (int n = 0; n < 4; ++n) {
      int col = wn + n * 16 + ocol;
      float bi = bp[col];
#pragma unroll
      for (int ii = 0; ii < 4; ++ii) {
        int gr = rowBase + wm + m * 16 + orow + ii;
        if (gr >= M) continue;
        out[(size_t)gr * D + col] = acc[m][n][ii] + bi;
      }
    }
  }
}

// ======================= per-node attention v3 =======================
// One wave per node; 4 edges in flight (16-lane groups); software-pipelined
// loads (ssrc/ea/kv for batch i+1 issued during batch i) + defer-max softmax.
__global__ __launch_bounds__(256) void node_attn_kernel(
    const ushort* __restrict__ q, const ushort* __restrict__ kv,
    const ushort* __restrict__ xr, ushort* __restrict__ g,
    const float* __restrict__ qwe, const uint4* __restrict__ easrt,
    const float* __restrict__ We, const float* __restrict__ Wb,
    const int* __restrict__ off, const int* __restrict__ ssrc, int N)
{
  const int wid = threadIdx.x >> 6;
  const int lane = threadIdx.x & 63;
  const int node = blockIdx.x * 4 + wid;
  if (node >= N) return;
  const int grp = lane >> 4;
  const int i = lane & 15;
  const int di = i * 8;
  const int head = i >> 3;

  float qr[8];
  {
    uint4 qa = *(const uint4*)(q + (size_t)node * D + di);
    qr[0] = blo(qa.x); qr[1] = bhi(qa.x); qr[2] = blo(qa.y); qr[3] = bhi(qa.y);
    qr[4] = blo(qa.z); qr[5] = bhi(qa.z); qr[6] = blo(qa.w); qr[7] = bhi(qa.w);
  }
  float qw[5];
  {
    const float* qp = qwe + (size_t)node * 16 + head * 8;
    float4 t = *(const float4*)qp;
    qw[0] = t.x; qw[1] = t.y; qw[2] = t.z; qw[3] = t.w; qw[4] = qp[4];
  }

  const int beg = off[node], end = off[node + 1];
  float m = -INFINITY, s = 0.f;
  float o[8] = {0.f, 0.f, 0.f, 0.f, 0.f, 0.f, 0.f, 0.f};
  float wea[5] = {0.f, 0.f, 0.f, 0.f, 0.f};

  if (beg < end) {
    int p0 = beg + grp;
    bool valid_c = p0 < end;
    int pl = valid_c ? p0 : beg;
    int src_c = ssrc[pl];
    uint4 eau_c = easrt[pl];
    const ushort* kp0 = kv + (size_t)src_c * (2 * D);
    uint4 ku_c = *(const uint4*)(kp0 + di);
    uint4 vu_c = *(const uint4*)(kp0 + D + di);

    for (int pb = beg; pb < end; pb += 4) {
      // ---- prefetch indices for next batch (clamped to last-touched) ----
      int pn = pb + 4 + grp;
      bool valid_n = pn < end;
      int pln = valid_n ? pn : pl;
      int src_n = ssrc[pln];
      uint4 eau_n = easrt[pln];

      // ---- alpha from current regs ----
      float ea0 = blo(eau_c.x), ea1 = bhi(eau_c.x), ea2 = blo(eau_c.y),
            ea3 = bhi(eau_c.y), ea4 = blo(eau_c.z);
      float part = qr[0] * blo(ku_c.x) + qr[1] * bhi(ku_c.x)
                 + qr[2] * blo(ku_c.y) + qr[3] * bhi(ku_c.y)
                 + qr[4] * blo(ku_c.z) + qr[5] * bhi(ku_c.z)
                 + qr[6] * blo(ku_c.w) + qr[7] * bhi(ku_c.w);
#pragma unroll
      for (int ofs = 1; ofs < 8; ofs <<= 1) part += __shfl_xor(part, ofs, 64);
      float eadot = qw[0] * ea0 + qw[1] * ea1 + qw[2] * ea2 + qw[3] * ea3 + qw[4] * ea4;
      float alpha = valid_c ? (part + eadot) : -INFINITY;

      // ---- prefetch next kv (src_n should have landed during the dot) ----
      const ushort* kpn = kv + (size_t)src_n * (2 * D);
      uint4 ku_n = *(const uint4*)(kpn + di);
      uint4 vu_n = *(const uint4*)(kpn + D + di);

      float v0 = blo(vu_c.x), v1 = bhi(vu_c.x), v2 = blo(vu_c.y), v3 = bhi(vu_c.y),
            v4 = blo(vu_c.z), v5 = bhi(vu_c.z), v6 = blo(vu_c.w), v7 = bhi(vu_c.w);

      // ---- defer-max online softmax ----
      if (__any(alpha > m + 8.f)) {
        float nm = fmaxf(m, alpha);
        float scale = (m > -1e30f) ? __expf(m - nm) : 0.f;
        float pw = (alpha > -1e30f) ? __expf(alpha - nm) : 0.f;
        m = nm;
        s = s * scale + pw;
        o[0] = o[0] * scale + pw * v0; o[1] = o[1] * scale + pw * v1;
        o[2] = o[2] * scale + pw * v2; o[3] = o[3] * scale + pw * v3;
        o[4] = o[4] * scale + pw * v4; o[5] = o[5] * scale + pw * v5;
        o[6] = o[6] * scale + pw * v6; o[7] = o[7] * scale + pw * v7;
        wea[0] = wea[0] * scale + pw * ea0; wea[1] = wea[1] * scale + pw * ea1;
        wea[2] = wea[2] * scale + pw * ea2; wea[3] = wea[3] * scale + pw * ea3;
        wea[4] = wea[4] * scale + pw * ea4;
      } else {
        float pw = (alpha > -1e30f) ? __expf(alpha - m) : 0.f;
        s += pw;
        o[0] += pw * v0; o[1] += pw * v1; o[2] += pw * v2; o[3] += pw * v3;
        o[4] += pw * v4; o[5] += pw * v5; o[6] += pw * v6; o[7] += pw * v7;
        wea[0] += pw * ea0; wea[1] += pw * ea1; wea[2] += pw * ea2;
        wea[3] += pw * ea3; wea[4] += pw * ea4;
      }

      ku_c = ku_n; vu_c = vu_n; eau_c = eau_n; valid_c = valid_n; pl = pln;
    }
  }

  // merge the 4 groups (lane bits 4,5)
#pragma unroll
  for (int ofs = 16; ofs < 64; ofs <<= 1) {
    float m2 = __shfl_xor(m, ofs, 64);
    float s2 = __shfl_xor(s, ofs, 64);
    float o2[8], w2[5];
#pragma unroll
    for (int j = 0; j < 8; ++j) o2[j] = __shfl_xor(o[j], ofs, 64);
#pragma unroll
    for (int j = 0; j < 5; ++j) w2[j] = __shfl_xor(wea[j], ofs, 64);
    float nm = fmaxf(m, m2);
    float e1 = (m > -1e30f) ? __expf(m - nm) : 0.f;
    float e2 = (m2 > -1e30f) ? __expf(m2 - nm) : 0.f;
    s = s * e1 + s2 * e2;
#pragma unroll
    for (int j = 0; j < 8; ++j) o[j] = o[j] * e1 + o2[j] * e2;
#pragma unroll
    for (int j = 0; j < 5; ++j) wea[j] = wea[j] * e1 + w2[j] * e2;
    m = nm;
  }

  float inv = (s > 0.f) ? (1.f / s) : 0.f;
#pragma unroll
  for (int j = 0; j < 8; ++j) o[j] *= inv;
#pragma unroll
  for (int j = 0; j < 5; ++j) wea[j] *= inv;

  // O += We @ wea for this lane's 8 dims
  {
    const float* wp = We + (size_t)di * EDIM;
    float4 w[10];
#pragma unroll
    for (int t = 0; t < 10; ++t) w[t] = *(const float4*)(wp + 4 * t);
#pragma unroll
    for (int r = 0; r < 8; ++r)
#pragma unroll
      for (int j = 0; j < 5; ++j) {
        int idx = r * 5 + j;
        o[r] += wea[j] * ((const float*)&w[idx >> 2])[idx & 3];
      }
  }

  // beta gate
  float xrv[8];
  {
    uint4 xa = *(const uint4*)(xr + (size_t)node * D + di);
    xrv[0] = blo(xa.x); xrv[1] = bhi(xa.x); xrv[2] = blo(xa.y); xrv[3] = bhi(xa.y);
    xrv[4] = blo(xa.z); xrv[5] = bhi(xa.z); xrv[6] = blo(xa.w); xrv[7] = bhi(xa.w);
  }
  float part = 0.f;
#pragma unroll
  for (int r = 0; r < 8; ++r) {
    float w1 = Wb[di + r] + Wb[256 + di + r];
    float w2 = Wb[128 + di + r] - Wb[256 + di + r];
    part += o[r] * w1 + xrv[r] * w2;
  }
#pragma unroll
  for (int ofs = 1; ofs < 16; ofs <<= 1) part += __shfl_xor(part, ofs, 64);
  float beta = 1.f / (1.f + __expf(-part));

  if (grp == 0) {
    uint pk[4];
#pragma unroll
    for (int r = 0; r < 4; ++r) {
      float g0 = beta * xrv[2 * r] + (1.f - beta) * o[2 * r];
      float g1 = beta * xrv[2 * r + 1] + (1.f - beta) * o[2 * r + 1];
      pk[r] = (uint)f2b(g0) | ((uint)f2b(g1) << 16);
    }
    *(uint4*)(g + (size_t)node * D + di) = make_uint4(pk[0], pk[1], pk[2], pk[3]);
  }
}

// ======================= launch =======================

extern "C" void kernel_launch(void* const* d_in, const int* in_sizes, int n_in,
                              void* d_out, int out_size, void* d_ws, size_t ws_size,
                              hipStream_t stream)
{
  const float* x  = (const float*)d_in[0];
  const int*   ei = (const int*)d_in[1];
  const float* ea = (const float*)d_in[2];
  const float* Wq = (const float*)d_in[3];
  const float* bq = (const float*)d_in[4];
  const float* Wk = (const float*)d_in[5];
  const float* bk = (const float*)d_in[6];
  const float* Wv = (const float*)d_in[7];
  const float* bv = (const float*)d_in[8];
  const float* We = (const float*)d_in[9];
  const float* Wr = (const float*)d_in[10];
  const float* br = (const float*)d_in[11];
  const float* Wb = (const float*)d_in[12];
  const float* Wp = (const float*)d_in[13];
  const float* bp = (const float*)d_in[14];

  const int N = in_sizes[0] / D;
  const int E = in_sizes[1] / 2;
  float* out = (float*)d_out;

  char* ws = (char*)d_ws;
  size_t o = 0;
  auto alloc = [&](size_t bytes) -> void* {
    void* p = ws + o;
    o = (o + bytes + 255) & ~(size_t)255;
    return p;
  };
  ushort* q      = (ushort*)alloc((size_t)N * D * sizeof(ushort));
  ushort* kv     = (ushort*)alloc((size_t)N * 2 * D * sizeof(ushort));
  ushort* xr     = (ushort*)alloc((size_t)N * D * sizeof(ushort));
  ushort* g      = (ushort*)alloc((size_t)N * D * sizeof(ushort));
  float*  qwe    = (float*)alloc((size_t)N * 16 * sizeof(float));
  ushort* Wcat   = (ushort*)alloc((size_t)640 * D * sizeof(ushort));
  float*  bcat   = (float*)alloc(640 * sizeof(float));
  ushort* Wpb    = (ushort*)alloc((size_t)D * D * sizeof(ushort));
  int*    deg    = (int*)alloc((size_t)N * sizeof(int));
  int*    cursor = (int*)alloc((size_t)N * sizeof(int));
  int*    offs   = (int*)alloc((size_t)(N + 1) * sizeof(int));
  int*    ssrc   = (int*)alloc((size_t)E * sizeof(int));
  uint4*  easrt  = (uint4*)alloc((size_t)E * sizeof(uint4));
  int*    bsum   = (int*)alloc(64 * sizeof(int));
  int*    bbase  = (int*)alloc(64 * sizeof(int));

  const int n4 = N / 4;                    // N divisible by 4
  const int nb = (n4 + 255) / 256;         // scan blocks (<= 64)

  zero_int_kernel<<<(N + 255) / 256, 256, 0, stream>>>(deg, N);
  hist_kernel<<<(E + 255) / 256, 256, 0, stream>>>(ei, deg, E);
  scan_p1<<<nb, 256, 0, stream>>>(deg, offs, bsum, n4);
  scan_p2<<<1, 64, 0, stream>>>(bsum, bbase, offs + N, nb);
  scan_p3<<<nb, 256, 0, stream>>>(offs, bbase, cursor, n4);
  scatter_kernel<<<(E + 255) / 256, 256, 0, stream>>>(ei, ea, offs, cursor, ssrc, easrt, E);

  cvt_w_kernel<<<(512 * D + 128 * D + 255) / 256, 256, 0, stream>>>(
      Wq, Wk, Wv, Wr, bq, bk, bv, br, We, Wp, Wcat, bcat, Wpb);

  proj_gemm_kernel<<<(N + 63) / 64, 256, 0, stream>>>(x, Wcat, bcat, q, kv, xr, qwe, N);

  node_attn_kernel<<<(N + 3) / 4, 256, 0, stream>>>(q, kv, xr, g, qwe, easrt, We, Wb,
                                                    offs, ssrc, N);

  out_gemm_kernel<<<(N + 63) / 64, 256, 0, stream>>>(g, Wpb, bp, out, N);
}

// Round 7
// 215.440 us; speedup vs baseline: 2.8445x; 1.1195x over previous
//
#include <hip/hip_runtime.h>
#include <stdint.h>
#include <math.h>

#define D 128
#define EDIM 5
#define QSCALE 0.1803368801111204f   // 0.125 * log2(e)

typedef __attribute__((ext_vector_type(8))) short bf16x8;
typedef __attribute__((ext_vector_type(4))) float f32x4;

__device__ __forceinline__ float fexp2(float x) {
  return __builtin_amdgcn_exp2f(x);    // v_exp_f32 (2^x)
}

__device__ __forceinline__ ushort f2b(float f) {
  union { float f; uint u; } v; v.f = f;
  uint u = v.u;
  return (ushort)((u + 0x7fff + ((u >> 16) & 1)) >> 16);   // RNE
}
__device__ __forceinline__ float blo(uint u) {
  union { uint u; float f; } v; v.u = u << 16; return v.f;
}
__device__ __forceinline__ float bhi(uint u) {
  union { uint u; float f; } v; v.u = u & 0xffff0000u; return v.f;
}

// ======================= utility kernels =======================

__global__ void hist_kernel(const int* __restrict__ ei, int* __restrict__ deg, int E) {
  int e = blockIdx.x * blockDim.x + threadIdx.x;
  if (e < E) atomicAdd(&deg[ei[(size_t)E + e]], 1);
}

// ---- hierarchical exclusive scan over deg[N] -> off[N+1] ----
__global__ __launch_bounds__(256) void scan_p1(const int* __restrict__ deg,
                                               int* __restrict__ off,
                                               int* __restrict__ blockSum, int n4) {
  __shared__ int waveTot[4];
  int idx = blockIdx.x * 256 + threadIdx.x;
  int4 v = make_int4(0, 0, 0, 0);
  if (idx < n4) v = ((const int4*)deg)[idx];
  int c0 = v.x, c1 = c0 + v.y, c2 = c1 + v.z, c3 = c2 + v.w;
  int tot = c3;
  int lane = threadIdx.x & 63, w = threadIdx.x >> 6;
  int incl = tot;
#pragma unroll
  for (int ofs = 1; ofs < 64; ofs <<= 1) {
    int t = __shfl_up(incl, ofs, 64);
    if (lane >= ofs) incl += t;
  }
  if (lane == 63) waveTot[w] = incl;
  __syncthreads();
  int wbase = 0;
  for (int i = 0; i < w; ++i) wbase += waveTot[i];
  int excl = wbase + incl - tot;
  if (idx < n4) {
    int4 o;
    o.x = excl; o.y = excl + c0; o.z = excl + c1; o.w = excl + c2;
    ((int4*)off)[idx] = o;
  }
  if (threadIdx.x == 255) blockSum[blockIdx.x] = wbase + incl;
}

__global__ void scan_p2(const int* __restrict__ blockSum, int* __restrict__ blockBase,
                        int* __restrict__ off_last, int nb) {
  int lane = threadIdx.x;            // 64 threads, nb <= 64
  int v = (lane < nb) ? blockSum[lane] : 0;
  int incl = v;
#pragma unroll
  for (int ofs = 1; ofs < 64; ofs <<= 1) {
    int t = __shfl_up(incl, ofs, 64);
    if (lane >= ofs) incl += t;
  }
  if (lane < nb) blockBase[lane] = incl - v;
  if (lane == 63) *off_last = incl;
}

// add block bases; also zero cursor
__global__ __launch_bounds__(256) void scan_p3(int* __restrict__ off,
                                               const int* __restrict__ blockBase,
                                               int* __restrict__ cursor, int n4) {
  int idx = blockIdx.x * 256 + threadIdx.x;
  if (idx >= n4) return;
  int b = blockBase[blockIdx.x];
  int4 v = ((int4*)off)[idx];
  v.x += b; v.y += b; v.z += b; v.w += b;
  ((int4*)off)[idx] = v;
  ((int4*)cursor)[idx] = make_int4(0, 0, 0, 0);
}

// sort edges by dst; edge payload = {ea bf16 x5, src} in ONE uint4
__global__ void scatter_kernel(const int* __restrict__ ei, const float* __restrict__ ea,
                               const int* __restrict__ off, int* __restrict__ cursor,
                               uint4* __restrict__ easrt, int E) {
  int e = blockIdx.x * blockDim.x + threadIdx.x;
  if (e >= E) return;
  int dst = ei[(size_t)E + e];
  int pos = off[dst] + atomicAdd(&cursor[dst], 1);
  const float* p = ea + (size_t)e * EDIM;
  uint e0 = f2b(p[0]), e1 = f2b(p[1]), e2 = f2b(p[2]), e3 = f2b(p[3]), e4 = f2b(p[4]);
  easrt[pos] = make_uint4(e0 | (e1 << 16), e2 | (e3 << 16), e4, (uint)ei[e]);
}

// ======================= weight prep (+ deg zero fused) =======================
// Wcat[640][128] bf16: rows 0-127 Wq*QSCALE, 128-255 Wk, 256-383 Wv, 384-511 Wskip,
// rows 512-639: composite qwe rows (row 512+h*8+j = sum_{d in head h} We[d][j]*QSCALE*Wq[d][:])
__global__ void cvt_w_kernel(const float* __restrict__ Wq, const float* __restrict__ Wk,
                             const float* __restrict__ Wv, const float* __restrict__ Wr,
                             const float* __restrict__ bq, const float* __restrict__ bk,
                             const float* __restrict__ bv, const float* __restrict__ br,
                             const float* __restrict__ We, const float* __restrict__ Wp,
                             ushort* __restrict__ Wcat, float* __restrict__ bcat,
                             ushort* __restrict__ Wpb, int* __restrict__ deg, int N) {
  int i = blockIdx.x * blockDim.x + threadIdx.x;
  if (i < N) deg[i] = 0;
  if (i < 512 * D) {
    int r = i >> 7;
    float v;
    if (r < 128)      v = Wq[i] * QSCALE;
    else if (r < 256) v = Wk[i - 128 * D];
    else if (r < 384) v = Wv[i - 256 * D];
    else              v = Wr[i - 384 * D];
    Wcat[i] = f2b(v);
  } else if (i < 512 * D + 128 * D) {
    int ie = i - 512 * D;
    int r = ie >> 7, c = ie & 127;          // Wcat row 512+r
    int h = r >> 3, j = r & 7;
    float v = 0.f;
    if (h < 2 && j < 5) {
      for (int d = 0; d < 64; ++d) {
        int dd = h * 64 + d;
        v += We[(size_t)dd * EDIM + j] * QSCALE * Wq[(size_t)dd * D + c];
      }
    }
    Wcat[(size_t)(512 + r) * D + c] = f2b(v);
  }
  if (i < D * D) Wpb[i] = f2b(Wp[i]);
  if (i < 512) {
    float v = (i < 128) ? bq[i] * QSCALE
            : (i < 256) ? bk[i - 128]
            : (i < 384) ? bv[i - 256] : br[i - 384];
    bcat[i] = v;
  } else if (i < 640) {
    int t = i - 512;
    int h = t >> 3, j = t & 7;
    float v = 0.f;
    if (h < 2 && j < 5) {
      for (int d = 0; d < 64; ++d) {
        int dd = h * 64 + d;
        v += bq[dd] * QSCALE * We[(size_t)dd * EDIM + j];
      }
    }
    bcat[i] = v;
  }
}

// ======================= fused projection GEMM =======================
__global__ __launch_bounds__(256) void proj_gemm_kernel(
    const float* __restrict__ x, const ushort* __restrict__ Wcat,
    const float* __restrict__ bcat,
    ushort* __restrict__ q, ushort* __restrict__ kv, ushort* __restrict__ xr,
    float* __restrict__ qwe, int M)
{
  __shared__ __attribute__((aligned(16))) ushort As[64][128];
  __shared__ __attribute__((aligned(16))) ushort Bs[128][128];
  const int tid = threadIdx.x;
  const int rowBase = blockIdx.x * 64;

  // stage A with fused f32->bf16 convert
#pragma unroll
  for (int it = 0; it < 4; ++it) {
    int i = it * 256 + tid;
    int r = i >> 4, c = i & 15;
    int gr = rowBase + r;
    float4 a0 = make_float4(0.f, 0.f, 0.f, 0.f), a1 = a0;
    if (gr < M) {
      a0 = *(const float4*)(x + (size_t)gr * D + c * 8);
      a1 = *(const float4*)(x + (size_t)gr * D + c * 8 + 4);
    }
    uint4 w;
    w.x = (uint)f2b(a0.x) | ((uint)f2b(a0.y) << 16);
    w.y = (uint)f2b(a0.z) | ((uint)f2b(a0.w) << 16);
    w.z = (uint)f2b(a1.x) | ((uint)f2b(a1.y) << 16);
    w.w = (uint)f2b(a1.z) | ((uint)f2b(a1.w) << 16);
    *(uint4*)(&As[r][(c ^ (r & 7)) * 8]) = w;
  }

  const int lane = tid & 63;
  const int wave = tid >> 6;
  const int wm = (wave >> 1) * 32;
  const int wn = (wave & 1) * 64;
  const int lrow = lane & 15;
  const int kgrp = lane >> 4;
  const int orow = (lane >> 4) * 4;
  const int ocol = lane & 15;

  for (int cb = 0; cb < 5; ++cb) {
    // stage B block (cb=4: only rows 0-15 are live)
#pragma unroll
    for (int it = 0; it < 8; ++it) {
      int i = it * 256 + tid;
      int r = i >> 4, c = i & 15;
      if (cb == 4 && r >= 16) continue;
      uint4 bv4 = *(const uint4*)(Wcat + (size_t)(cb * 128 + r) * D + c * 8);
      *(uint4*)(&Bs[r][(c ^ (r & 7)) * 8]) = bv4;
    }
    __syncthreads();

    f32x4 acc[2][4] = {};
#pragma unroll
    for (int ks = 0; ks < 4; ++ks) {
      int chunk = ks * 4 + kgrp;
      bf16x8 a[2], b[4];
#pragma unroll
      for (int m = 0; m < 2; ++m) {
        int r = wm + m * 16 + lrow;
        a[m] = *(const bf16x8*)&As[r][(chunk ^ (r & 7)) * 8];
      }
#pragma unroll
      for (int n = 0; n < 4; ++n) {
        int r = wn + n * 16 + lrow;
        b[n] = *(const bf16x8*)&Bs[r][(chunk ^ (r & 7)) * 8];
      }
#pragma unroll
      for (int m = 0; m < 2; ++m)
#pragma unroll
        for (int n = 0; n < 4; ++n) {
          if (cb == 4 && (wn + n * 16) >= 16) continue;
          acc[m][n] = __builtin_amdgcn_mfma_f32_16x16x32_bf16(a[m], b[n], acc[m][n], 0, 0, 0);
        }
    }

#pragma unroll
    for (int m = 0; m < 2; ++m) {
#pragma unroll
      for (int n = 0; n < 4; ++n) {
        if (cb == 4 && (wn + n * 16) >= 16) continue;
        int col = cb * 128 + wn + n * 16 + ocol;
        float bi = bcat[col];
        int sel = col >> 7, c = col & 127;
#pragma unroll
        for (int ii = 0; ii < 4; ++ii) {
          int gr = rowBase + wm + m * 16 + orow + ii;
          if (gr >= M) continue;
          float v = acc[m][n][ii] + bi;
          if (sel == 0)      q[(size_t)gr * D + c] = f2b(v);
          else if (sel == 1) kv[(size_t)gr * 2 * D + c] = f2b(v);
          else if (sel == 2) kv[(size_t)gr * 2 * D + D + c] = f2b(v);
          else if (sel == 3) xr[(size_t)gr * D + c] = f2b(v);
          else if (c < 16)   qwe[(size_t)gr * 16 + c] = v;
        }
      }
    }
    __syncthreads();
  }
}

// ======================= output projection GEMM =======================
__global__ __launch_bounds__(256) void out_gemm_kernel(
    const ushort* __restrict__ g, const ushort* __restrict__ Wpb,
    const float* __restrict__ bp, float* __restrict__ out, int M)
{
  __shared__ __attribute__((aligned(16))) ushort As[64][128];
  __shared__ __attribute__((aligned(16))) ushort Bs[128][128];
  const int tid = threadIdx.x;
  const int rowBase = blockIdx.x * 64;

#pragma unroll
  for (int it = 0; it < 4; ++it) {
    int i = it * 256 + tid;
    int r = i >> 4, c = i & 15;
    int gr = rowBase + r;
    uint4 av = make_uint4(0, 0, 0, 0);
    if (gr < M) av = *(const uint4*)(g + (size_t)gr * D + c * 8);
    *(uint4*)(&As[r][(c ^ (r & 7)) * 8]) = av;
  }
#pragma unroll
  for (int it = 0; it < 8; ++it) {
    int i = it * 256 + tid;
    int r = i >> 4, c = i & 15;
    uint4 bv4 = *(const uint4*)(Wpb + (size_t)r * D + c * 8);
    *(uint4*)(&Bs[r][(c ^ (r & 7)) * 8]) = bv4;
  }
  __syncthreads();

  const int lane = tid & 63;
  const int wave = tid >> 6;
  const int wm = (wave >> 1) * 32;
  const int wn = (wave & 1) * 64;
  const int lrow = lane & 15;
  const int kgrp = lane >> 4;

  f32x4 acc[2][4] = {};
#pragma unroll
  for (int ks = 0; ks < 4; ++ks) {
    int chunk = ks * 4 + kgrp;
    bf16x8 a[2], b[4];
#pragma unroll
    for (int m = 0; m < 2; ++m) {
      int r = wm + m * 16 + lrow;
      a[m] = *(const bf16x8*)&As[r][(chunk ^ (r & 7)) * 8];
    }
#pragma unroll
    for (int n = 0; n < 4; ++n) {
      int r = wn + n * 16 + lrow;
      b[n] = *(const bf16x8*)&Bs[r][(chunk ^ (r & 7)) * 8];
    }
#pragma unroll
    for (int m = 0; m < 2; ++m)
#pragma unroll
      for (int n = 0; n < 4; ++n)
        acc[m][n] = __builtin_amdgcn_mfma_f32_16x16x32_bf16(a[m], b[n], acc[m][n], 0, 0, 0);
  }

  const int orow = (lane >> 4) * 4;
  const int ocol = lane & 15;
#pragma unroll
  for (int m = 0; m < 2; ++m) {
#pragma unroll
    for (int n = 0; n < 4; ++n) {
      int col = wn + n * 16 + ocol;
      float bi = bp[col];
#pragma unroll
      for (int ii = 0; ii < 4; ++ii) {
        int gr = rowBase + wm + m * 16 + orow + ii;
        if (gr >= M) continue;
        out[(size_t)gr * D + col] = acc[m][n][ii] + bi;
      }
    }
  }
}

// ======================= per-node attention v4 =======================
// One wave per node; 16-lane groups, 4 edges per batch; modulo-3 software
// pipeline: eau issued 3 batches ahead, K/V 2 batches ahead. exp2 domain.
__global__ __launch_bounds__(256) void node_attn_kernel(
    const ushort* __restrict__ q, const ushort* __restrict__ kv,
    const ushort* __restrict__ xr, ushort* __restrict__ g,
    const float* __restrict__ qwe, const uint4* __restrict__ easrt,
    const float* __restrict__ We, const float* __restrict__ Wb,
    const int* __restrict__ off, int N)
{
  const int wid = threadIdx.x >> 6;
  const int lane = threadIdx.x & 63;
  const int node = blockIdx.x * 4 + wid;
  if (node >= N) return;
  const int grp = lane >> 4;
  const int i = lane & 15;
  const int di = i * 8;
  const int head = i >> 3;

  float qr[8];
  {
    uint4 qa = *(const uint4*)(q + (size_t)node * D + di);
    qr[0] = blo(qa.x); qr[1] = bhi(qa.x); qr[2] = blo(qa.y); qr[3] = bhi(qa.y);
    qr[4] = blo(qa.z); qr[5] = bhi(qa.z); qr[6] = blo(qa.w); qr[7] = bhi(qa.w);
  }
  float qw[5];
  {
    const float* qp = qwe + (size_t)node * 16 + head * 8;
    float4 t = *(const float4*)qp;
    qw[0] = t.x; qw[1] = t.y; qw[2] = t.z; qw[3] = t.w; qw[4] = qp[4];
  }

  const int beg = off[node], end = off[node + 1];
  float m = -INFINITY, s = 0.f;
  float o[8] = {0.f, 0.f, 0.f, 0.f, 0.f, 0.f, 0.f, 0.f};
  float wea[5] = {0.f, 0.f, 0.f, 0.f, 0.f};

  if (beg < end) {
    const int em1 = end - 1;
    const int p0 = beg + grp;
    uint4 e0 = easrt[min(p0, em1)];
    uint4 e1 = easrt[min(p0 + 4, em1)];
    uint4 e2 = easrt[min(p0 + 8, em1)];
    const ushort* kp_;
    kp_ = kv + (size_t)e0.w * (2 * D);
    uint4 k0 = *(const uint4*)(kp_ + di), v0 = *(const uint4*)(kp_ + D + di);
    kp_ = kv + (size_t)e1.w * (2 * D);
    uint4 k1 = *(const uint4*)(kp_ + di), v1 = *(const uint4*)(kp_ + D + di);
    uint4 k2v = k0, v2v = v0;   // written by STEP1 before STEP3 reads them

#define ATT_STEP(PB, eA, eC, kA, vA, kC, vC)                                   \
    {                                                                          \
      int p = (PB) + grp;                                                      \
      bool valid = p < end;                                                    \
      /* issue K/V for batch PB+8 (addresses from eC, landed long ago) */      \
      const ushort* kpn = kv + (size_t)(eC).w * (2 * D);                       \
      (kC) = *(const uint4*)(kpn + di);                                        \
      (vC) = *(const uint4*)(kpn + D + di);                                    \
      /* unpack this batch's edge features, then reuse eA's slot */            \
      float ea0 = blo((eA).x), ea1 = bhi((eA).x), ea2 = blo((eA).y),           \
            ea3 = bhi((eA).y), ea4 = blo((eA).z);                              \
      (eA) = easrt[min(p + 12, em1)];                                          \
      /* alpha (log2 domain) */                                                \
      float part = qr[0] * blo((kA).x) + qr[1] * bhi((kA).x)                   \
                 + qr[2] * blo((kA).y) + qr[3] * bhi((kA).y)                   \
                 + qr[4] * blo((kA).z) + qr[5] * bhi((kA).z)                   \
                 + qr[6] * blo((kA).w) + qr[7] * bhi((kA).w);                  \
      part += __shfl_xor(part, 1, 64);                                         \
      part += __shfl_xor(part, 2, 64);                                         \
      part += __shfl_xor(part, 4, 64);                                         \
      float eadot = qw[0] * ea0 + qw[1] * ea1 + qw[2] * ea2 + qw[3] * ea3      \
                  + qw[4] * ea4;                                               \
      float alpha = valid ? (part + eadot) : -INFINITY;                        \
      float vv0 = blo((vA).x), vv1 = bhi((vA).x), vv2 = blo((vA).y),           \
            vv3 = bhi((vA).y), vv4 = blo((vA).z), vv5 = bhi((vA).z),           \
            vv6 = blo((vA).w), vv7 = bhi((vA).w);                              \
      if (__any(alpha > m + 11.5f)) {                                          \
        float nm = fmaxf(m, alpha);                                            \
        float scale = (m > -1e30f) ? fexp2(m - nm) : 0.f;                      \
        float pw = valid ? fexp2(alpha - nm) : 0.f;                            \
        m = nm;                                                                \
        s = s * scale + pw;                                                    \
        o[0] = o[0] * scale + pw * vv0; o[1] = o[1] * scale + pw * vv1;        \
        o[2] = o[2] * scale + pw * vv2; o[3] = o[3] * scale + pw * vv3;        \
        o[4] = o[4] * scale + pw * vv4; o[5] = o[5] * scale + pw * vv5;        \
        o[6] = o[6] * scale + pw * vv6; o[7] = o[7] * scale + pw * vv7;        \
        wea[0] = wea[0] * scale + pw * ea0; wea[1] = wea[1] * scale + pw * ea1;\
        wea[2] = wea[2] * scale + pw * ea2; wea[3] = wea[3] * scale + pw * ea3;\
        wea[4] = wea[4] * scale + pw * ea4;                                    \
      } else {                                                                 \
        float pw = valid ? fexp2(alpha - m) : 0.f;                             \
        s += pw;                                                               \
        o[0] += pw * vv0; o[1] += pw * vv1; o[2] += pw * vv2;                  \
        o[3] += pw * vv3; o[4] += pw * vv4; o[5] += pw * vv5;                  \
        o[6] += pw * vv6; o[7] += pw * vv7;                                    \
        wea[0] += pw * ea0; wea[1] += pw * ea1; wea[2] += pw * ea2;            \
        wea[3] += pw * ea3; wea[4] += pw * ea4;                                \
      }                                                                        \
    }

    for (int pb = beg; pb < end; pb += 12) {
      ATT_STEP(pb,     e0, e2, k0, v0, k2v, v2v)
      ATT_STEP(pb + 4, e1, e0, k1, v1, k0, v0)
      ATT_STEP(pb + 8, e2, e1, k2v, v2v, k1, v1)
    }
#undef ATT_STEP
  }

  // merge the 4 groups (lane bits 4,5)
#pragma unroll
  for (int ofs = 16; ofs < 64; ofs <<= 1) {
    float m2 = __shfl_xor(m, ofs, 64);
    float s2 = __shfl_xor(s, ofs, 64);
    float o2[8], w2[5];
#pragma unroll
    for (int j = 0; j < 8; ++j) o2[j] = __shfl_xor(o[j], ofs, 64);
#pragma unroll
    for (int j = 0; j < 5; ++j) w2[j] = __shfl_xor(wea[j], ofs, 64);
    float nm = fmaxf(m, m2);
    float e1m = (m > -1e30f) ? fexp2(m - nm) : 0.f;
    float e2m = (m2 > -1e30f) ? fexp2(m2 - nm) : 0.f;
    s = s * e1m + s2 * e2m;
#pragma unroll
    for (int j = 0; j < 8; ++j) o[j] = o[j] * e1m + o2[j] * e2m;
#pragma unroll
    for (int j = 0; j < 5; ++j) wea[j] = wea[j] * e1m + w2[j] * e2m;
    m = nm;
  }

  float inv = (s > 0.f) ? (1.f / s) : 0.f;
#pragma unroll
  for (int j = 0; j < 8; ++j) o[j] *= inv;
#pragma unroll
  for (int j = 0; j < 5; ++j) wea[j] *= inv;

  // O += We @ wea for this lane's 8 dims
  {
    const float* wp = We + (size_t)di * EDIM;
    float4 w[10];
#pragma unroll
    for (int t = 0; t < 10; ++t) w[t] = *(const float4*)(wp + 4 * t);
#pragma unroll
    for (int r = 0; r < 8; ++r)
#pragma unroll
      for (int j = 0; j < 5; ++j) {
        int idx = r * 5 + j;
        o[r] += wea[j] * ((const float*)&w[idx >> 2])[idx & 3];
      }
  }

  // beta gate
  float xrv[8];
  {
    uint4 xa = *(const uint4*)(xr + (size_t)node * D + di);
    xrv[0] = blo(xa.x); xrv[1] = bhi(xa.x); xrv[2] = blo(xa.y); xrv[3] = bhi(xa.y);
    xrv[4] = blo(xa.z); xrv[5] = bhi(xa.z); xrv[6] = blo(xa.w); xrv[7] = bhi(xa.w);
  }
  float part = 0.f;
#pragma unroll
  for (int r = 0; r < 8; ++r) {
    float w1 = Wb[di + r] + Wb[256 + di + r];
    float w2 = Wb[128 + di + r] - Wb[256 + di + r];
    part += o[r] * w1 + xrv[r] * w2;
  }
#pragma unroll
  for (int ofs = 1; ofs < 16; ofs <<= 1) part += __shfl_xor(part, ofs, 64);
  float beta = 1.f / (1.f + __expf(-part));

  if (grp == 0) {
    uint pk[4];
#pragma unroll
    for (int r = 0; r < 4; ++r) {
      float g0 = beta * xrv[2 * r] + (1.f - beta) * o[2 * r];
      float g1 = beta * xrv[2 * r + 1] + (1.f - beta) * o[2 * r + 1];
      pk[r] = (uint)f2b(g0) | ((uint)f2b(g1) << 16);
    }
    *(uint4*)(g + (size_t)node * D + di) = make_uint4(pk[0], pk[1], pk[2], pk[3]);
  }
}

// ======================= launch =======================

extern "C" void kernel_launch(void* const* d_in, const int* in_sizes, int n_in,
                              void* d_out, int out_size, void* d_ws, size_t ws_size,
                              hipStream_t stream)
{
  const float* x  = (const float*)d_in[0];
  const int*   ei = (const int*)d_in[1];
  const float* ea = (const float*)d_in[2];
  const float* Wq = (const float*)d_in[3];
  const float* bq = (const float*)d_in[4];
  const float* Wk = (const float*)d_in[5];
  const float* bk = (const float*)d_in[6];
  const float* Wv = (const float*)d_in[7];
  const float* bv = (const float*)d_in[8];
  const float* We = (const float*)d_in[9];
  const float* Wr = (const float*)d_in[10];
  const float* br = (const float*)d_in[11];
  const float* Wb = (const float*)d_in[12];
  const float* Wp = (const float*)d_in[13];
  const float* bp = (const float*)d_in[14];

  const int N = in_sizes[0] / D;
  const int E = in_sizes[1] / 2;
  float* out = (float*)d_out;

  char* ws = (char*)d_ws;
  size_t o = 0;
  auto alloc = [&](size_t bytes) -> void* {
    void* p = ws + o;
    o = (o + bytes + 255) & ~(size_t)255;
    return p;
  };
  ushort* q      = (ushort*)alloc((size_t)N * D * sizeof(ushort));
  ushort* kv     = (ushort*)alloc((size_t)N * 2 * D * sizeof(ushort));
  ushort* xr     = (ushort*)alloc((size_t)N * D * sizeof(ushort));
  ushort* g      = (ushort*)alloc((size_t)N * D * sizeof(ushort));
  float*  qwe    = (float*)alloc((size_t)N * 16 * sizeof(float));
  ushort* Wcat   = (ushort*)alloc((size_t)640 * D * sizeof(ushort));
  float*  bcat   = (float*)alloc(640 * sizeof(float));
  ushort* Wpb    = (ushort*)alloc((size_t)D * D * sizeof(ushort));
  int*    deg    = (int*)alloc((size_t)N * sizeof(int));
  int*    cursor = (int*)alloc((size_t)N * sizeof(int));
  int*    offs   = (int*)alloc((size_t)(N + 1) * sizeof(int));
  uint4*  easrt  = (uint4*)alloc((size_t)E * sizeof(uint4));
  int*    bsum   = (int*)alloc(64 * sizeof(int));
  int*    bbase  = (int*)alloc(64 * sizeof(int));

  const int n4 = N / 4;                    // N divisible by 4
  const int nb = (n4 + 255) / 256;         // scan blocks (<= 64)

  // weight prep first (also zeroes deg)
  cvt_w_kernel<<<(512 * D + 128 * D + 255) / 256, 256, 0, stream>>>(
      Wq, Wk, Wv, Wr, bq, bk, bv, br, We, Wp, Wcat, bcat, Wpb, deg, N);

  hist_kernel<<<(E + 255) / 256, 256, 0, stream>>>(ei, deg, E);
  scan_p1<<<nb, 256, 0, stream>>>(deg, offs, bsum, n4);
  scan_p2<<<1, 64, 0, stream>>>(bsum, bbase, offs + N, nb);
  scan_p3<<<nb, 256, 0, stream>>>(offs, bbase, cursor, n4);
  scatter_kernel<<<(E + 255) / 256, 256, 0, stream>>>(ei, ea, offs, cursor, easrt, E);

  proj_gemm_kernel<<<(N + 63) / 64, 256, 0, stream>>>(x, Wcat, bcat, q, kv, xr, qwe, N);

  node_attn_kernel<<<(N + 3) / 4, 256, 0, stream>>>(q, kv, xr, g, qwe, easrt, We, Wb,
                                                    offs, N);

  out_gemm_kernel<<<(N + 63) / 64, 256, 0, stream>>>(g, Wpb, bp, out, N);
}